// Round 5
// baseline (330.659 us; speedup 1.0000x reference)
//
#include <hip/hip_runtime.h>
#include <cstdint>
#include <cstddef>

typedef unsigned short u16;
typedef __attribute__((ext_vector_type(8))) short bf16x8;
typedef __attribute__((ext_vector_type(8))) unsigned short u16x8;
typedef __attribute__((ext_vector_type(4))) unsigned short u16x4;
typedef __attribute__((ext_vector_type(4))) float f32x4;

__device__ __forceinline__ unsigned short f2bf(float f) {
    union { float f; uint32_t u; } c; c.f = f;
    uint32_t u = c.u + 0x7fffu + ((c.u >> 16) & 1u);
    return (unsigned short)(u >> 16);
}
__device__ __forceinline__ float bf2f(unsigned short h) {
    union { uint32_t u; float f; } c; c.u = ((uint32_t)h) << 16;
    return c.f;
}
// single-instruction pack: low16 = bf16(a), high16 = bf16(b)
__device__ __forceinline__ uint32_t cvtpk(float a, float b) {
    uint32_t r;
    asm("v_cvt_pk_bf16_f32 %0, %1, %2" : "=v"(r) : "v"(a), "v"(b));
    return r;
}

#define GLDS16(g, l)                                                               \
    __builtin_amdgcn_global_load_lds((const __attribute__((address_space(1))) void*)(g), \
                                     (__attribute__((address_space(3))) void*)(l), 16, 0, 0)

// ---------------------------------------------------------------------------
// fp32 -> bf16 straight convert (x).
// ---------------------------------------------------------------------------
__global__ __launch_bounds__(256) void cvt_x(const float* __restrict__ src,
                                             u16* __restrict__ dst) {
    int i = blockIdx.x * 256 + threadIdx.x;
    const float4* s = (const float4*)src + (size_t)i * 2;
    float4 a = s[0], b = s[1];
    u16x8 o;
    o[0] = f2bf(a.x); o[1] = f2bf(a.y); o[2] = f2bf(a.z); o[3] = f2bf(a.w);
    o[4] = f2bf(b.x); o[5] = f2bf(b.y); o[6] = f2bf(b.z); o[7] = f2bf(b.w);
    *(u16x8*)(dst + (size_t)i * 8) = o;
}

// ---------------------------------------------------------------------------
// Transpose-convert: src fp32 [2048 k][C n] -> dst bf16 [C n][2048 k].
// ---------------------------------------------------------------------------
__global__ __launch_bounds__(256) void tcvt(const float* __restrict__ src,
                                            u16* __restrict__ dst, int C) {
    __shared__ u16 tile[32][33];
    const int t = threadIdx.x;
    const int bx = blockIdx.x, by = blockIdx.y;
    const int tr = t >> 3, tc = (t & 7) << 2;
    float4 f = *(const float4*)&src[(size_t)(by * 32 + tr) * C + bx * 32 + tc];
    tile[tr][tc + 0] = f2bf(f.x); tile[tr][tc + 1] = f2bf(f.y);
    tile[tr][tc + 2] = f2bf(f.z); tile[tr][tc + 3] = f2bf(f.w);
    __syncthreads();
    u16x4 o;
    o[0] = tile[tc + 0][tr]; o[1] = tile[tc + 1][tr];
    o[2] = tile[tc + 2][tr]; o[3] = tile[tc + 3][tr];
    *(u16x4*)&dst[(size_t)(bx * 32 + tr) * 2048 + by * 32 + tc] = o;
}

// Merged transpose-convert for Wq|Wk|Wv -> wqkvt (one launch).
__global__ __launch_bounds__(256) void tcvt3(const float* __restrict__ Wq,
                                             const float* __restrict__ Wk,
                                             const float* __restrict__ Wv,
                                             u16* __restrict__ dst) {
    __shared__ u16 tile[32][33];
    const int t = threadIdx.x;
    const int bxg = blockIdx.x, by = blockIdx.y;
    const float* src; int C, nb; u16* dbase;
    if (bxg < 64)      { src = Wq; C = 2048; nb = bxg;      dbase = dst; }
    else if (bxg < 80) { src = Wk; C = 512;  nb = bxg - 64; dbase = dst + (size_t)2048 * 2048; }
    else               { src = Wv; C = 512;  nb = bxg - 80; dbase = dst + (size_t)2560 * 2048; }
    const int tr = t >> 3, tc = (t & 7) << 2;
    float4 f = *(const float4*)&src[(size_t)(by * 32 + tr) * C + nb * 32 + tc];
    tile[tr][tc + 0] = f2bf(f.x); tile[tr][tc + 1] = f2bf(f.y);
    tile[tr][tc + 2] = f2bf(f.z); tile[tr][tc + 3] = f2bf(f.w);
    __syncthreads();
    u16x4 o;
    o[0] = tile[tc + 0][tr]; o[1] = tile[tc + 1][tr];
    o[2] = tile[tc + 2][tr]; o[3] = tile[tc + 3][tr];
    *(u16x4*)&dbase[(size_t)(nb * 32 + tr) * 2048 + by * 32 + tc] = o;
}

// ---------------------------------------------------------------------------
// m97-style GEMM (kept for the output projection): C = A * Bt^T, MODE 1 only.
// ---------------------------------------------------------------------------
template <int MODE>
__global__ __launch_bounds__(256) void gemm2(const u16* __restrict__ A,
                                             const u16* __restrict__ Bt,
                                             u16* __restrict__ oq, u16* __restrict__ ok,
                                             u16* __restrict__ ov, float* __restrict__ of) {
    __shared__ u16 As[128 * 32];
    __shared__ u16 Bs[128 * 32];
    const int t = threadIdx.x, w = t >> 6, lane = t & 63;
    const int l15 = lane & 15, quad = lane >> 4;
    const int m0 = blockIdx.y << 7, n0 = blockIdx.x << 7;
    const int K = 2048;
    const int c0 = w * 2, c1 = c0 + 1;
    const int ar0 = c0 * 16 + (lane >> 2), ar1 = c1 * 16 + (lane >> 2);
    const int ac = (lane & 3) << 3;
    const u16* Ap0 = A + (size_t)(m0 + ar0) * K + ac;
    const u16* Ap1 = A + (size_t)(m0 + ar1) * K + ac;
    const u16* Bp0 = Bt + (size_t)(n0 + ar0) * K + ac;
    const u16* Bp1 = Bt + (size_t)(n0 + ar1) * K + ac;
    const int wm = (w >> 1) << 6, wn = (w & 1) << 6;

    f32x4 acc[4][4] = {};

    for (int k0 = 0; k0 < K; k0 += 32) {
        GLDS16(Ap0 + k0, &As[c0 * 512]);
        GLDS16(Ap1 + k0, &As[c1 * 512]);
        GLDS16(Bp0 + k0, &Bs[c0 * 512]);
        GLDS16(Bp1 + k0, &Bs[c1 * 512]);
        __syncthreads();
        bf16x8 a[4], bfr[4];
#pragma unroll
        for (int mt = 0; mt < 4; ++mt)
            a[mt] = *(bf16x8*)&As[(wm + mt * 16 + l15) * 32 + quad * 8];
#pragma unroll
        for (int nt = 0; nt < 4; ++nt)
            bfr[nt] = *(bf16x8*)&Bs[(wn + nt * 16 + l15) * 32 + quad * 8];
#pragma unroll
        for (int mt = 0; mt < 4; ++mt)
#pragma unroll
            for (int nt = 0; nt < 4; ++nt)
                acc[mt][nt] = __builtin_amdgcn_mfma_f32_16x16x32_bf16(a[mt], bfr[nt], acc[mt][nt], 0, 0, 0);
        __syncthreads();
    }

#pragma unroll
    for (int mt = 0; mt < 4; ++mt)
#pragma unroll
        for (int nt = 0; nt < 4; ++nt)
#pragma unroll
            for (int r = 0; r < 4; ++r) {
                int row = m0 + wm + mt * 16 + quad * 4 + r;
                int col = n0 + wn + nt * 16 + l15;
                of[(size_t)row * 2048 + col] = acc[mt][nt][r];
            }
}

// ---------------------------------------------------------------------------
// gemm8p: QKV projection, 256x256 tile, BK=64, 8 waves, 8-phase schedule
// (T2 swizzle + T3/T4 counted vmcnt + T5 setprio; m201 template class).
//   - LDS 128KB: [buf2][A|B][half2][128 rows][64 u16], rows 128B, 16B slots
//     XOR-swizzled: slot s of row r holds global slot s^(r&7). Staged by
//     global_load_lds with PRE-SWIZZLED per-lane global source (m173).
//   - 8 phases / iteration; 2 K-tiles (even->buf0, odd->buf1) per iteration.
//     Phase = {ds_read frags; issue stage; s_barrier; lgkmcnt(0);
//              setprio(1); 16 MFMA; setprio(0); [vmcnt]; s_barrier}.
//     Stage slots (derived region-liveness-safe):
//       ph1: A0(odd) ph2: A1(odd) ph4: B0,B1(even+2)+vmcnt(4)
//       ph5: A0(even+2) ph6: A1(even+2) ph8: B0,B1(odd+2)+vmcnt(4)
//     vmcnt(4) leaves exactly the current phase's 4 loads -> every half-tile
//     lands >=1 phase before first read; every stage issues >=1 barrier after
//     its region's last read. Raw s_barrier (no __syncthreads drain).
//   - Epilogue: fused RoPE (Q,K) + V^T store; wave 64-col span = one head.
// ---------------------------------------------------------------------------
__global__ __launch_bounds__(512, 1) void gemm8p(const u16* __restrict__ A,
                                                 const u16* __restrict__ Bt,
                                                 u16* __restrict__ oq, u16* __restrict__ ok,
                                                 u16* __restrict__ ov) {
    __shared__ u16 lds[65536];   // 128 KB

    const int t = threadIdx.x, w = t >> 6, lane = t & 63;
    const int l15 = lane & 15, quad = lane >> 4;
    const int wm = w >> 2, wn = w & 3;
    const int m0 = blockIdx.y << 8, n0 = blockIdx.x << 8;
    const int K = 2048;
    const int NIT = 16;          // 32 K-tiles of 64, 2 per iteration

    // pre-swizzled per-lane stage source: row m0/n0 + w*8 + (lane>>3),
    // col-slot (lane&7)^(lane>>3)  [r&7 == lane>>3 for every staged row]
    const int srow = w * 8 + (lane >> 3);
    const int scol = ((lane & 7) ^ (lane >> 3)) << 3;
    const u16* pA = A + (size_t)(m0 + srow) * K + scol;
    const u16* pB = Bt + (size_t)(n0 + srow) * K + scol;

// stage one half-tile (128 rows x 64 cols): 2 global_load_lds per wave
#define STG(AB, BUF, HF, T) do {                                                   \
    const u16* _s = ((AB) ? pB : pA) + (size_t)((HF) * 128) * K + (size_t)(T) * 64; \
    u16* _d = &lds[(BUF) * 32768 + (AB) * 16384 + (HF) * 8192 + w * 512];          \
    GLDS16(_s, _d);                                                                \
    GLDS16(_s + (size_t)64 * K, _d + 4096);                                        \
} while (0)

// ds_read fragment blocks (swizzled addressing; all indices compile-time)
#define RD_A(BUF, MQ)                                                              \
    _Pragma("unroll") for (int fi = 0; fi < 4; ++fi)                               \
    _Pragma("unroll") for (int ks = 0; ks < 2; ++ks) {                             \
        int r_ = (MQ) * 64 + fi * 16 + l15;                                        \
        int u_ = ks * 4 + quad;                                                    \
        a_[fi][ks] = *(const bf16x8*)&lds[(BUF) * 32768 + wm * 8192 + r_ * 64 +    \
                                          ((u_ ^ (r_ & 7)) << 3)];                 \
    }
#define RD_B(BUF, NQ)                                                              \
    _Pragma("unroll") for (int fj = 0; fj < 2; ++fj)                               \
    _Pragma("unroll") for (int ks = 0; ks < 2; ++ks) {                             \
        int r_ = (wn & 1) * 64 + (NQ) * 32 + fj * 16 + l15;                        \
        int u_ = ks * 4 + quad;                                                    \
        b_[fj][ks] = *(const bf16x8*)&lds[(BUF) * 32768 + 16384 + (wn >> 1) * 8192 \
                                          + r_ * 64 + ((u_ ^ (r_ & 7)) << 3)];     \
    }
#define MFMA16(MQ, NQ)                                                             \
    __builtin_amdgcn_s_barrier();                                                  \
    asm volatile("s_waitcnt lgkmcnt(0)" ::: "memory");                             \
    __builtin_amdgcn_sched_barrier(0);                                             \
    __builtin_amdgcn_s_setprio(1);                                                 \
    _Pragma("unroll") for (int fi = 0; fi < 4; ++fi)                               \
    _Pragma("unroll") for (int fj = 0; fj < 2; ++fj) {                             \
        acc[(MQ) * 4 + fi][(NQ) * 2 + fj] = __builtin_amdgcn_mfma_f32_16x16x32_bf16( \
            a_[fi][0], b_[fj][0], acc[(MQ) * 4 + fi][(NQ) * 2 + fj], 0, 0, 0);     \
        acc[(MQ) * 4 + fi][(NQ) * 2 + fj] = __builtin_amdgcn_mfma_f32_16x16x32_bf16( \
            a_[fi][1], b_[fj][1], acc[(MQ) * 4 + fi][(NQ) * 2 + fj], 0, 0, 0);     \
    }                                                                              \
    __builtin_amdgcn_s_setprio(0);

    f32x4 acc[8][4] = {};
    bf16x8 a_[4][2], b_[2][2];

    // prologue: tile0 A0,A1,B0,B1 -> buf0; tile1 B0,B1 -> buf1 (12 loads)
    STG(0, 0, 0, 0); STG(0, 0, 1, 0);
    STG(1, 0, 0, 0); STG(1, 0, 1, 0);
    STG(1, 1, 0, 1); STG(1, 1, 1, 1);
    asm volatile("s_waitcnt vmcnt(4)" ::: "memory");   // tile0 landed
    __builtin_amdgcn_s_barrier();

    for (int it = 0; it < NIT; ++it) {
        const bool more = (it + 1 < NIT);
        const int o = 2 * it + 1, e2 = 2 * it + 2, o2 = 2 * it + 3;

        // ph1: buf0 (mq0,nq0); stage A0(odd) -> buf1
        RD_A(0, 0); RD_B(0, 0);
        STG(0, 1, 0, o);
        MFMA16(0, 0);
        __builtin_amdgcn_s_barrier();

        // ph2: buf0 (mq1,nq0) [B reuse]; stage A1(odd) -> buf1
        RD_A(0, 1);
        STG(0, 1, 1, o);
        MFMA16(1, 0);
        __builtin_amdgcn_s_barrier();

        // ph3: buf0 (mq0,nq1)
        RD_A(0, 0); RD_B(0, 1);
        MFMA16(0, 1);
        __builtin_amdgcn_s_barrier();

        // ph4: buf0 (mq1,nq1); stage B0,B1(even+2) -> buf0; vmcnt
        RD_A(0, 1);
        if (more) { STG(1, 0, 0, e2); STG(1, 0, 1, e2); }
        MFMA16(1, 1);
        if (more) asm volatile("s_waitcnt vmcnt(4)" ::: "memory");
        else      asm volatile("s_waitcnt vmcnt(0)" ::: "memory");
        __builtin_amdgcn_s_barrier();

        // ph5: buf1 (mq0,nq0); stage A0(even+2) -> buf0
        RD_A(1, 0); RD_B(1, 0);
        if (more) STG(0, 0, 0, e2);
        MFMA16(0, 0);
        __builtin_amdgcn_s_barrier();

        // ph6: buf1 (mq1,nq0); stage A1(even+2) -> buf0
        RD_A(1, 1);
        if (more) STG(0, 0, 1, e2);
        MFMA16(1, 0);
        __builtin_amdgcn_s_barrier();

        // ph7: buf1 (mq0,nq1)
        RD_A(1, 0); RD_B(1, 1);
        MFMA16(0, 1);
        __builtin_amdgcn_s_barrier();

        // ph8: buf1 (mq1,nq1); stage B0,B1(odd+2) -> buf1; vmcnt
        RD_A(1, 1);
        if (more) { STG(1, 1, 0, o2); STG(1, 1, 1, o2); }
        MFMA16(1, 1);
        if (more) asm volatile("s_waitcnt vmcnt(4)" ::: "memory");
        else      asm volatile("s_waitcnt vmcnt(0)" ::: "memory");
        __builtin_amdgcn_s_barrier();
    }
#undef STG
#undef RD_A
#undef RD_B
#undef MFMA16

    // ---------------- epilogue: RoPE (Q,K) / V^T, same layout as before ----
    const int colbase = n0 + wn * 64;
    const bool isv = (colbase >= 2560);
    float iv[4];
    if (!isv) {
#pragma unroll
        for (int nj = 0; nj < 4; ++nj)
            iv[nj] = exp2f(-0.4152410118609253f * (float)(nj * 8 + (l15 >> 1)));
    }
    const int map1 = (quad << 4) | ((2 * l15 + 1) & 15);  // odd partners (d<32)
    const int map2 = (quad << 4) | ((2 * l15) & 15);      // even partners (d>=32)
    const bool lo = (l15 < 8);
#pragma unroll
    for (int mi = 0; mi < 8; ++mi)
#pragma unroll
        for (int r = 0; r < 4; ++r) {
            const int row = m0 + wm * 128 + mi * 16 + quad * 4 + r;
            float v0 = acc[mi][0][r], v1 = acc[mi][1][r];
            float v2 = acc[mi][2][r], v3 = acc[mi][3][r];
            float o0 = v0, o1 = v1, o2 = v2, o3 = v3;
            if (!isv) {
                float g1a = __shfl(v0, map1), g1b = __shfl(v1, map1);
                float g1c = __shfl(v2, map1), g1d = __shfl(v3, map1);
                float g2a = __shfl(v0, map2), g2b = __shfl(v1, map2);
                float g2c = __shfl(v2, map2), g2d = __shfl(v3, map2);
                float p0 = lo ? g1a : g1b;
                float p1 = lo ? g1c : g1d;
                float p2 = lo ? g2a : g2b;
                float p3 = lo ? g2c : g2d;
                const float tt = (float)(row & 2047);
                float sn, cs;
                __sincosf(tt * iv[0], &sn, &cs); o0 = v0 * cs - p0 * sn;
                __sincosf(tt * iv[1], &sn, &cs); o1 = v1 * cs - p1 * sn;
                __sincosf(tt * iv[2], &sn, &cs); o2 = v2 * cs + p2 * sn;
                __sincosf(tt * iv[3], &sn, &cs); o3 = v3 * cs + p3 * sn;
            }
            float oo[4] = {o0, o1, o2, o3};
            if (colbase < 2048) {
#pragma unroll
                for (int nj = 0; nj < 4; ++nj)
                    oq[(size_t)row * 2048 + colbase + nj * 16 + l15] = f2bf(oo[nj]);
            } else if (colbase < 2560) {
#pragma unroll
                for (int nj = 0; nj < 4; ++nj)
                    ok[(size_t)row * 512 + colbase - 2048 + nj * 16 + l15] = f2bf(oo[nj]);
            } else {
#pragma unroll
                for (int nj = 0; nj < 4; ++nj)
                    ov[(size_t)(colbase - 2560 + nj * 16 + l15) * 4096 + row] = f2bf(oo[nj]);
            }
        }
}

// ---------------------------------------------------------------------------
// Flash attention v8 (R4, verified 310.8us config) — unchanged.
// launch_bounds(256,2): VGPR cap 128, kernel needs ~120, no spill.
// ---------------------------------------------------------------------------
__global__ __launch_bounds__(256, 2) void attn8(const u16* __restrict__ q,
                                                const u16* __restrict__ k,
                                                const u16* __restrict__ vT,
                                                u16* __restrict__ att) {
    __shared__ u16 Ks[64 * 64];         // [key][d] swizzled, 128B rows
    __shared__ u16 Vt[64 * 64];         // [d][key] swizzled
    __shared__ u16 Pw[4][2][16 * 64];   // per (wave, stream) P^T, swizzled

    const int t = threadIdx.x, w = t >> 6, lane = t & 63;
    const int l15 = lane & 15, quad = lane >> 4;
    const int id = blockIdx.x;
    const int kvh = id & 7;
    const int z = (id >> 3) & 1;
    const int gi = id >> 4;             // 0..63
    const int p = gi & 15;
    int g;
    switch (gi >> 4) {
        case 0:  g = 63 - p; break;
        case 1:  g = 32 + p; break;
        case 2:  g = 31 - p; break;
        default: g = p;      break;
    }
    const int h = kvh * 4 + w;
    const size_t rowbase = (size_t)z * 2048;
    const float SC = 0.125f * 1.4426950408889634f;  // 1/sqrt(64) * log2(e)
    const int swz = l15 & 7;

    const int srow = t >> 3;            // 0..31 (second row = srow+32)
    const int slot = t & 7;
    const int sd = slot << 3;
    const int lidx = srow * 64 + ((slot ^ (srow & 7)) << 3);

    const u16* kbase = &k[(rowbase + srow) * 512 + kvh * 64 + sd];
    const u16* vbase = &vT[(size_t)(kvh * 64 + srow) * 4096 + rowbase + sd];

    const int ntiles = (g >> 1) + 1;
    const int qrow0 = g * 32;

    bf16x8 aq[2][2];
#pragma unroll
    for (int m = 0; m < 2; ++m)
#pragma unroll
        for (int kc = 0; kc < 2; ++kc)
            aq[m][kc] = *(const bf16x8*)&q[(rowbase + qrow0 + m * 16 + l15) * 2048 +
                                           h * 64 + kc * 32 + quad * 8];

    f32x4 acc[2][4] = {};
    float m_i[2] = {-INFINITY, -INFINITY};
    float l_i[2] = {0.f, 0.f};

    u16x8 pk0 = *(const u16x8*)kbase;
    u16x8 pk1 = *(const u16x8*)(kbase + (size_t)32 * 512);
    u16x8 pv0 = *(const u16x8*)vbase;
    u16x8 pv1 = *(const u16x8*)(vbase + (size_t)32 * 4096);

    for (int kb = 0; kb < ntiles; ++kb) {
        __syncthreads();
        *(u16x8*)&Ks[lidx]        = pk0;
        *(u16x8*)&Ks[lidx + 2048] = pk1;
        *(u16x8*)&Vt[lidx]        = pv0;
        *(u16x8*)&Vt[lidx + 2048] = pv1;
        if (kb + 1 < ntiles) {
            const u16* kp = kbase + (size_t)(kb + 1) * 64 * 512;
            pk0 = *(const u16x8*)kp;
            pk1 = *(const u16x8*)(kp + (size_t)32 * 512);
            const u16* vp = vbase + (size_t)(kb + 1) * 64;
            pv0 = *(const u16x8*)vp;
            pv1 = *(const u16x8*)(vp + (size_t)32 * 4096);
        }
        __syncthreads();

        f32x4 st[2][4] = {};
        __builtin_amdgcn_s_setprio(1);
#pragma unroll
        for (int kt = 0; kt < 4; ++kt) {
            bf16x8 ak0 = *(const bf16x8*)&Ks[(kt * 16 + l15) * 64 + ((quad ^ swz) << 3)];
            bf16x8 ak1 = *(const bf16x8*)&Ks[(kt * 16 + l15) * 64 + (((quad + 4) ^ swz) << 3)];
#pragma unroll
            for (int m = 0; m < 2; ++m) {
                st[m][kt] = __builtin_amdgcn_mfma_f32_16x16x32_bf16(ak0, aq[m][0], st[m][kt], 0, 0, 0);
                st[m][kt] = __builtin_amdgcn_mfma_f32_16x16x32_bf16(ak1, aq[m][1], st[m][kt], 0, 0, 0);
            }
        }
        __builtin_amdgcn_s_setprio(0);

        const bool diag = (kb == ntiles - 1);
        float alpha_[2];
        bool resc[2];
#pragma unroll
        for (int m = 0; m < 2; ++m) {
            float sv[16];
#pragma unroll
            for (int kt = 0; kt < 4; ++kt)
#pragma unroll
                for (int r = 0; r < 4; ++r) sv[kt * 4 + r] = st[m][kt][r];
            if (diag) {
                const int qg = qrow0 + m * 16 + l15;
#pragma unroll
                for (int kt = 0; kt < 4; ++kt)
#pragma unroll
                    for (int r = 0; r < 4; ++r) {
                        int key = kb * 64 + kt * 16 + quad * 4 + r;
                        if (key > qg) sv[kt * 4 + r] = -INFINITY;
                    }
            }
            float mx = sv[0];
#pragma unroll
            for (int i = 1; i < 16; ++i) mx = fmaxf(mx, sv[i]);
            mx = fmaxf(mx, __shfl_xor(mx, 16));
            mx = fmaxf(mx, __shfl_xor(mx, 32));
            mx *= SC;
            const float mold = m_i[m];
            const bool need = __any(mx > mold + 8.f);
            float al = 1.f;
            if (need) {
                const float mnew = fmaxf(mold, mx);
                al = __builtin_amdgcn_exp2f(mold - mnew);
                m_i[m] = mnew;
            }
            const float mu = m_i[m];
            float sum = 0.f;
#pragma unroll
            for (int i = 0; i < 16; ++i) {
                sv[i] = __builtin_amdgcn_exp2f(fmaf(sv[i], SC, -mu));
                sum += sv[i];
            }
            sum += __shfl_xor(sum, 16);
            sum += __shfl_xor(sum, 32);
            l_i[m] = l_i[m] * al + sum;
            alpha_[m] = al;
            resc[m] = need;

            u16* Pq = &Pw[w][m][0];
#pragma unroll
            for (int kt = 0; kt < 4; ++kt) {
                uint2 uu;
                uu.x = cvtpk(sv[kt * 4 + 0], sv[kt * 4 + 1]);
                uu.y = cvtpk(sv[kt * 4 + 2], sv[kt * 4 + 3]);
                *(uint2*)&Pq[l15 * 64 + (((2 * kt + (quad >> 1)) ^ swz) << 3) + ((quad & 1) << 2)] = uu;
            }
        }

#pragma unroll
        for (int m = 0; m < 2; ++m)
            if (resc[m]) {
                const float al = alpha_[m];
#pragma unroll
                for (int dt = 0; dt < 4; ++dt)
#pragma unroll
                    for (int r = 0; r < 4; ++r) acc[m][dt][r] *= al;
            }

        bf16x8 bp[2][2];
#pragma unroll
        for (int m = 0; m < 2; ++m) {
            const u16* Pq = &Pw[w][m][0];
            bp[m][0] = *(const bf16x8*)&Pq[l15 * 64 + ((quad ^ swz) << 3)];
            bp[m][1] = *(const bf16x8*)&Pq[l15 * 64 + (((quad + 4) ^ swz) << 3)];
        }

        __builtin_amdgcn_s_setprio(1);
#pragma unroll
        for (int dt = 0; dt < 4; ++dt) {
            bf16x8 av0 = *(const bf16x8*)&Vt[(dt * 16 + l15) * 64 + ((quad ^ swz) << 3)];
            bf16x8 av1 = *(const bf16x8*)&Vt[(dt * 16 + l15) * 64 + (((quad + 4) ^ swz) << 3)];
#pragma unroll
            for (int m = 0; m < 2; ++m) {
                acc[m][dt] = __builtin_amdgcn_mfma_f32_16x16x32_bf16(av0, bp[m][0], acc[m][dt], 0, 0, 0);
                acc[m][dt] = __builtin_amdgcn_mfma_f32_16x16x32_bf16(av1, bp[m][1], acc[m][dt], 0, 0, 0);
            }
        }
        __builtin_amdgcn_s_setprio(0);
    }

#pragma unroll
    for (int m = 0; m < 2; ++m) {
        float inv = 1.0f / l_i[m];
        size_t row = rowbase + qrow0 + m * 16 + l15;
#pragma unroll
        for (int dt = 0; dt < 4; ++dt) {
            uint2 uu;
            uu.x = cvtpk(acc[m][dt][0] * inv, acc[m][dt][1] * inv);
            uu.y = cvtpk(acc[m][dt][2] * inv, acc[m][dt][3] * inv);
            *(uint2*)&att[row * 2048 + h * 64 + dt * 16 + quad * 4] = uu;
        }
    }
}

// ---------------------------------------------------------------------------
extern "C" void kernel_launch(void* const* d_in, const int* in_sizes, int n_in,
                              void* d_out, int out_size, void* d_ws, size_t ws_size,
                              hipStream_t stream) {
    const float* x  = (const float*)d_in[0];
    const float* Wq = (const float*)d_in[2];
    const float* Wk = (const float*)d_in[3];
    const float* Wv = (const float*)d_in[4];
    const float* Wo = (const float*)d_in[5];
    float* out = (float*)d_out;

    u16* xb = (u16*)d_out;                                   // bf16 x in d_out (dead before final write)

    u16* q     = (u16*)d_ws;                                 // 4096x2048
    u16* kk    = q + (size_t)4096 * 2048;                    // 4096x512
    u16* vt    = kk + (size_t)4096 * 512;                    // 512x4096 (V^T)
    u16* wqkvt = vt + (size_t)4096 * 512;                    // 3072x2048 (dead after QKV gemm)
    u16* att   = wqkvt;                                      // 4096x2048 aliases dead wqkvt
    u16* wot   = kk;                                         // 2048x2048 aliases dead kk+vt (after attn)

    cvt_x<<<4096, 256, 0, stream>>>(x, xb);
    tcvt3<<<dim3(96, 64), 256, 0, stream>>>(Wq, Wk, Wv, wqkvt);
    gemm8p<<<dim3(12, 16), 512, 0, stream>>>(xb, wqkvt, q, kk, vt);  // 8-phase QKV + rope
    attn8<<<1024, 256, 0, stream>>>(q, kk, vt, att);
    tcvt<<<dim3(64, 64), 256, 0, stream>>>(Wo, wot, 2048);
    gemm2<1><<<dim3(16, 32), 256, 0, stream>>>(att, wot, nullptr, nullptr, nullptr, out);
}

// Round 6
// 328.417 us; speedup vs baseline: 1.0068x; 1.0068x over previous
//
#include <hip/hip_runtime.h>
#include <cstdint>
#include <cstddef>

typedef unsigned short u16;
typedef __attribute__((ext_vector_type(8))) short bf16x8;
typedef __attribute__((ext_vector_type(8))) unsigned short u16x8;
typedef __attribute__((ext_vector_type(4))) unsigned short u16x4;
typedef __attribute__((ext_vector_type(4))) float f32x4;

__device__ __forceinline__ unsigned short f2bf(float f) {
    union { float f; uint32_t u; } c; c.f = f;
    uint32_t u = c.u + 0x7fffu + ((c.u >> 16) & 1u);
    return (unsigned short)(u >> 16);
}
__device__ __forceinline__ float bf2f(unsigned short h) {
    union { uint32_t u; float f; } c; c.u = ((uint32_t)h) << 16;
    return c.f;
}
// single-instruction pack: low16 = bf16(a), high16 = bf16(b)
__device__ __forceinline__ uint32_t cvtpk(float a, float b) {
    uint32_t r;
    asm("v_cvt_pk_bf16_f32 %0, %1, %2" : "=v"(r) : "v"(a), "v"(b));
    return r;
}

#define GLDS16(g, l)                                                               \
    __builtin_amdgcn_global_load_lds((const __attribute__((address_space(1))) void*)(g), \
                                     (__attribute__((address_space(3))) void*)(l), 16, 0, 0)

// ---------------------------------------------------------------------------
// fp32 -> bf16 straight convert (x).
// ---------------------------------------------------------------------------
__global__ __launch_bounds__(256) void cvt_x(const float* __restrict__ src,
                                             u16* __restrict__ dst) {
    int i = blockIdx.x * 256 + threadIdx.x;
    const float4* s = (const float4*)src + (size_t)i * 2;
    float4 a = s[0], b = s[1];
    u16x8 o;
    o[0] = f2bf(a.x); o[1] = f2bf(a.y); o[2] = f2bf(a.z); o[3] = f2bf(a.w);
    o[4] = f2bf(b.x); o[5] = f2bf(b.y); o[6] = f2bf(b.z); o[7] = f2bf(b.w);
    *(u16x8*)(dst + (size_t)i * 8) = o;
}

// ---------------------------------------------------------------------------
// Transpose-convert: src fp32 [2048 k][C n] -> dst bf16 [C n][2048 k].
// ---------------------------------------------------------------------------
__global__ __launch_bounds__(256) void tcvt(const float* __restrict__ src,
                                            u16* __restrict__ dst, int C) {
    __shared__ u16 tile[32][33];
    const int t = threadIdx.x;
    const int bx = blockIdx.x, by = blockIdx.y;
    const int tr = t >> 3, tc = (t & 7) << 2;
    float4 f = *(const float4*)&src[(size_t)(by * 32 + tr) * C + bx * 32 + tc];
    tile[tr][tc + 0] = f2bf(f.x); tile[tr][tc + 1] = f2bf(f.y);
    tile[tr][tc + 2] = f2bf(f.z); tile[tr][tc + 3] = f2bf(f.w);
    __syncthreads();
    u16x4 o;
    o[0] = tile[tc + 0][tr]; o[1] = tile[tc + 1][tr];
    o[2] = tile[tc + 2][tr]; o[3] = tile[tc + 3][tr];
    *(u16x4*)&dst[(size_t)(bx * 32 + tr) * 2048 + by * 32 + tc] = o;
}

// Merged transpose-convert for Wq|Wk|Wv -> wqkvt (one launch).
__global__ __launch_bounds__(256) void tcvt3(const float* __restrict__ Wq,
                                             const float* __restrict__ Wk,
                                             const float* __restrict__ Wv,
                                             u16* __restrict__ dst) {
    __shared__ u16 tile[32][33];
    const int t = threadIdx.x;
    const int bxg = blockIdx.x, by = blockIdx.y;
    const float* src; int C, nb; u16* dbase;
    if (bxg < 64)      { src = Wq; C = 2048; nb = bxg;      dbase = dst; }
    else if (bxg < 80) { src = Wk; C = 512;  nb = bxg - 64; dbase = dst + (size_t)2048 * 2048; }
    else               { src = Wv; C = 512;  nb = bxg - 80; dbase = dst + (size_t)2560 * 2048; }
    const int tr = t >> 3, tc = (t & 7) << 2;
    float4 f = *(const float4*)&src[(size_t)(by * 32 + tr) * C + nb * 32 + tc];
    tile[tr][tc + 0] = f2bf(f.x); tile[tr][tc + 1] = f2bf(f.y);
    tile[tr][tc + 2] = f2bf(f.z); tile[tr][tc + 3] = f2bf(f.w);
    __syncthreads();
    u16x4 o;
    o[0] = tile[tc + 0][tr]; o[1] = tile[tc + 1][tr];
    o[2] = tile[tc + 2][tr]; o[3] = tile[tc + 3][tr];
    *(u16x4*)&dbase[(size_t)(nb * 32 + tr) * 2048 + by * 32 + tc] = o;
}

// ---------------------------------------------------------------------------
// m97-style GEMM (kept for the output projection): C = A * Bt^T, MODE 1 only.
// ---------------------------------------------------------------------------
template <int MODE>
__global__ __launch_bounds__(256) void gemm2(const u16* __restrict__ A,
                                             const u16* __restrict__ Bt,
                                             u16* __restrict__ oq, u16* __restrict__ ok,
                                             u16* __restrict__ ov, float* __restrict__ of) {
    __shared__ u16 As[128 * 32];
    __shared__ u16 Bs[128 * 32];
    const int t = threadIdx.x, w = t >> 6, lane = t & 63;
    const int l15 = lane & 15, quad = lane >> 4;
    const int m0 = blockIdx.y << 7, n0 = blockIdx.x << 7;
    const int K = 2048;
    const int c0 = w * 2, c1 = c0 + 1;
    const int ar0 = c0 * 16 + (lane >> 2), ar1 = c1 * 16 + (lane >> 2);
    const int ac = (lane & 3) << 3;
    const u16* Ap0 = A + (size_t)(m0 + ar0) * K + ac;
    const u16* Ap1 = A + (size_t)(m0 + ar1) * K + ac;
    const u16* Bp0 = Bt + (size_t)(n0 + ar0) * K + ac;
    const u16* Bp1 = Bt + (size_t)(n0 + ar1) * K + ac;
    const int wm = (w >> 1) << 6, wn = (w & 1) << 6;

    f32x4 acc[4][4] = {};

    for (int k0 = 0; k0 < K; k0 += 32) {
        GLDS16(Ap0 + k0, &As[c0 * 512]);
        GLDS16(Ap1 + k0, &As[c1 * 512]);
        GLDS16(Bp0 + k0, &Bs[c0 * 512]);
        GLDS16(Bp1 + k0, &Bs[c1 * 512]);
        __syncthreads();
        bf16x8 a[4], bfr[4];
#pragma unroll
        for (int mt = 0; mt < 4; ++mt)
            a[mt] = *(bf16x8*)&As[(wm + mt * 16 + l15) * 32 + quad * 8];
#pragma unroll
        for (int nt = 0; nt < 4; ++nt)
            bfr[nt] = *(bf16x8*)&Bs[(wn + nt * 16 + l15) * 32 + quad * 8];
#pragma unroll
        for (int mt = 0; mt < 4; ++mt)
#pragma unroll
            for (int nt = 0; nt < 4; ++nt)
                acc[mt][nt] = __builtin_amdgcn_mfma_f32_16x16x32_bf16(a[mt], bfr[nt], acc[mt][nt], 0, 0, 0);
        __syncthreads();
    }

#pragma unroll
    for (int mt = 0; mt < 4; ++mt)
#pragma unroll
        for (int nt = 0; nt < 4; ++nt)
#pragma unroll
            for (int r = 0; r < 4; ++r) {
                int row = m0 + wm + mt * 16 + quad * 4 + r;
                int col = n0 + wn + nt * 16 + l15;
                of[(size_t)row * 2048 + col] = acc[mt][nt][r];
            }
}

// ---------------------------------------------------------------------------
// gemm8p v2: QKV projection, 256x256 tile, BK=64, 8 waves, 8-phase schedule.
// R6 change vs R5: REMOVED the per-phase `s_waitcnt lgkmcnt(0)` +
// `sched_barrier(0)` order-pins (m141 lesson: order-pinning defeats the
// compiler's scheduler, ~1.7x). Compiler-generated ds_reads get precise
// fine-grained lgkmcnt from hipcc; cross-wave/buffer-reuse hazards remain
// fenced by the counted-vmcnt asm ("memory" clobber) at ph4/ph8 + barrier
// pairs (skew < 1 phase). Swizzle/staging layout identical to R5 (verified:
// bank conflicts = 0, absmax unchanged).
// ---------------------------------------------------------------------------
__global__ __launch_bounds__(512, 1) void gemm8p(const u16* __restrict__ A,
                                                 const u16* __restrict__ Bt,
                                                 u16* __restrict__ oq, u16* __restrict__ ok,
                                                 u16* __restrict__ ov) {
    __shared__ u16 lds[65536];   // 128 KB

    const int t = threadIdx.x, w = t >> 6, lane = t & 63;
    const int l15 = lane & 15, quad = lane >> 4;
    const int wm = w >> 2, wn = w & 3;
    const int m0 = blockIdx.y << 8, n0 = blockIdx.x << 8;
    const int K = 2048;
    const int NIT = 16;          // 32 K-tiles of 64, 2 per iteration

    // pre-swizzled per-lane stage source: row m0/n0 + w*8 + (lane>>3),
    // col-slot (lane&7)^(lane>>3)  [r&7 == lane>>3 for every staged row]
    const int srow = w * 8 + (lane >> 3);
    const int scol = ((lane & 7) ^ (lane >> 3)) << 3;
    const u16* pA = A + (size_t)(m0 + srow) * K + scol;
    const u16* pB = Bt + (size_t)(n0 + srow) * K + scol;

// stage one half-tile (128 rows x 64 cols): 2 global_load_lds per wave
#define STG(AB, BUF, HF, T) do {                                                   \
    const u16* _s = ((AB) ? pB : pA) + (size_t)((HF) * 128) * K + (size_t)(T) * 64; \
    u16* _d = &lds[(BUF) * 32768 + (AB) * 16384 + (HF) * 8192 + w * 512];          \
    GLDS16(_s, _d);                                                                \
    GLDS16(_s + (size_t)64 * K, _d + 4096);                                        \
} while (0)

// ds_read fragment blocks (swizzled addressing; all indices compile-time)
#define RD_A(BUF, MQ)                                                              \
    _Pragma("unroll") for (int fi = 0; fi < 4; ++fi)                               \
    _Pragma("unroll") for (int ks = 0; ks < 2; ++ks) {                             \
        int r_ = (MQ) * 64 + fi * 16 + l15;                                        \
        int u_ = ks * 4 + quad;                                                    \
        a_[fi][ks] = *(const bf16x8*)&lds[(BUF) * 32768 + wm * 8192 + r_ * 64 +    \
                                          ((u_ ^ (r_ & 7)) << 3)];                 \
    }
#define RD_B(BUF, NQ)                                                              \
    _Pragma("unroll") for (int fj = 0; fj < 2; ++fj)                               \
    _Pragma("unroll") for (int ks = 0; ks < 2; ++ks) {                             \
        int r_ = (wn & 1) * 64 + (NQ) * 32 + fj * 16 + l15;                        \
        int u_ = ks * 4 + quad;                                                    \
        b_[fj][ks] = *(const bf16x8*)&lds[(BUF) * 32768 + 16384 + (wn >> 1) * 8192 \
                                          + r_ * 64 + ((u_ ^ (r_ & 7)) << 3)];     \
    }
#define MFMA16(MQ, NQ)                                                             \
    __builtin_amdgcn_s_barrier();                                                  \
    __builtin_amdgcn_s_setprio(1);                                                 \
    _Pragma("unroll") for (int fi = 0; fi < 4; ++fi)                               \
    _Pragma("unroll") for (int fj = 0; fj < 2; ++fj) {                             \
        acc[(MQ) * 4 + fi][(NQ) * 2 + fj] = __builtin_amdgcn_mfma_f32_16x16x32_bf16( \
            a_[fi][0], b_[fj][0], acc[(MQ) * 4 + fi][(NQ) * 2 + fj], 0, 0, 0);     \
        acc[(MQ) * 4 + fi][(NQ) * 2 + fj] = __builtin_amdgcn_mfma_f32_16x16x32_bf16( \
            a_[fi][1], b_[fj][1], acc[(MQ) * 4 + fi][(NQ) * 2 + fj], 0, 0, 0);     \
    }                                                                              \
    __builtin_amdgcn_s_setprio(0);

    f32x4 acc[8][4] = {};
    bf16x8 a_[4][2], b_[2][2];

    // prologue: tile0 A0,A1,B0,B1 -> buf0; tile1 B0,B1 -> buf1 (12 loads)
    STG(0, 0, 0, 0); STG(0, 0, 1, 0);
    STG(1, 0, 0, 0); STG(1, 0, 1, 0);
    STG(1, 1, 0, 1); STG(1, 1, 1, 1);
    asm volatile("s_waitcnt vmcnt(4)" ::: "memory");   // tile0 landed
    __builtin_amdgcn_s_barrier();

    for (int it = 0; it < NIT; ++it) {
        const bool more = (it + 1 < NIT);
        const int o = 2 * it + 1, e2 = 2 * it + 2, o2 = 2 * it + 3;

        // ph1: buf0 (mq0,nq0); stage A0(odd) -> buf1
        RD_A(0, 0); RD_B(0, 0);
        STG(0, 1, 0, o);
        MFMA16(0, 0);
        __builtin_amdgcn_s_barrier();

        // ph2: buf0 (mq1,nq0) [B reuse]; stage A1(odd) -> buf1
        RD_A(0, 1);
        STG(0, 1, 1, o);
        MFMA16(1, 0);
        __builtin_amdgcn_s_barrier();

        // ph3: buf0 (mq0,nq1)
        RD_A(0, 0); RD_B(0, 1);
        MFMA16(0, 1);
        __builtin_amdgcn_s_barrier();

        // ph4: buf0 (mq1,nq1); stage B0,B1(even+2) -> buf0; vmcnt
        RD_A(0, 1);
        if (more) { STG(1, 0, 0, e2); STG(1, 0, 1, e2); }
        MFMA16(1, 1);
        if (more) asm volatile("s_waitcnt vmcnt(4)" ::: "memory");
        else      asm volatile("s_waitcnt vmcnt(0)" ::: "memory");
        __builtin_amdgcn_s_barrier();

        // ph5: buf1 (mq0,nq0); stage A0(even+2) -> buf0
        RD_A(1, 0); RD_B(1, 0);
        if (more) STG(0, 0, 0, e2);
        MFMA16(0, 0);
        __builtin_amdgcn_s_barrier();

        // ph6: buf1 (mq1,nq0); stage A1(even+2) -> buf0
        RD_A(1, 1);
        if (more) STG(0, 0, 1, e2);
        MFMA16(1, 0);
        __builtin_amdgcn_s_barrier();

        // ph7: buf1 (mq0,nq1)
        RD_A(1, 0); RD_B(1, 1);
        MFMA16(0, 1);
        __builtin_amdgcn_s_barrier();

        // ph8: buf1 (mq1,nq1); stage B0,B1(odd+2) -> buf1; vmcnt
        RD_A(1, 1);
        if (more) { STG(1, 1, 0, o2); STG(1, 1, 1, o2); }
        MFMA16(1, 1);
        if (more) asm volatile("s_waitcnt vmcnt(4)" ::: "memory");
        else      asm volatile("s_waitcnt vmcnt(0)" ::: "memory");
        __builtin_amdgcn_s_barrier();
    }
#undef STG
#undef RD_A
#undef RD_B
#undef MFMA16

    // ---------------- epilogue: RoPE (Q,K) / V^T, same layout as before ----
    const int colbase = n0 + wn * 64;
    const bool isv = (colbase >= 2560);
    float iv[4];
    if (!isv) {
#pragma unroll
        for (int nj = 0; nj < 4; ++nj)
            iv[nj] = exp2f(-0.4152410118609253f * (float)(nj * 8 + (l15 >> 1)));
    }
    const int map1 = (quad << 4) | ((2 * l15 + 1) & 15);  // odd partners (d<32)
    const int map2 = (quad << 4) | ((2 * l15) & 15);      // even partners (d>=32)
    const bool lo = (l15 < 8);
#pragma unroll
    for (int mi = 0; mi < 8; ++mi)
#pragma unroll
        for (int r = 0; r < 4; ++r) {
            const int row = m0 + wm * 128 + mi * 16 + quad * 4 + r;
            float v0 = acc[mi][0][r], v1 = acc[mi][1][r];
            float v2 = acc[mi][2][r], v3 = acc[mi][3][r];
            float o0 = v0, o1 = v1, o2 = v2, o3 = v3;
            if (!isv) {
                float g1a = __shfl(v0, map1), g1b = __shfl(v1, map1);
                float g1c = __shfl(v2, map1), g1d = __shfl(v3, map1);
                float g2a = __shfl(v0, map2), g2b = __shfl(v1, map2);
                float g2c = __shfl(v2, map2), g2d = __shfl(v3, map2);
                float p0 = lo ? g1a : g1b;
                float p1 = lo ? g1c : g1d;
                float p2 = lo ? g2a : g2b;
                float p3 = lo ? g2c : g2d;
                const float tt = (float)(row & 2047);
                float sn, cs;
                __sincosf(tt * iv[0], &sn, &cs); o0 = v0 * cs - p0 * sn;
                __sincosf(tt * iv[1], &sn, &cs); o1 = v1 * cs - p1 * sn;
                __sincosf(tt * iv[2], &sn, &cs); o2 = v2 * cs + p2 * sn;
                __sincosf(tt * iv[3], &sn, &cs); o3 = v3 * cs + p3 * sn;
            }
            float oo[4] = {o0, o1, o2, o3};
            if (colbase < 2048) {
#pragma unroll
                for (int nj = 0; nj < 4; ++nj)
                    oq[(size_t)row * 2048 + colbase + nj * 16 + l15] = f2bf(oo[nj]);
            } else if (colbase < 2560) {
#pragma unroll
                for (int nj = 0; nj < 4; ++nj)
                    ok[(size_t)row * 512 + colbase - 2048 + nj * 16 + l15] = f2bf(oo[nj]);
            } else {
#pragma unroll
                for (int nj = 0; nj < 4; ++nj)
                    ov[(size_t)(colbase - 2560 + nj * 16 + l15) * 4096 + row] = f2bf(oo[nj]);
            }
        }
}

// ---------------------------------------------------------------------------
// Flash attention v8 (R4, verified 310.8us config) — unchanged.
// launch_bounds(256,2): VGPR cap 128, kernel needs ~120, no spill.
// ---------------------------------------------------------------------------
__global__ __launch_bounds__(256, 2) void attn8(const u16* __restrict__ q,
                                                const u16* __restrict__ k,
                                                const u16* __restrict__ vT,
                                                u16* __restrict__ att) {
    __shared__ u16 Ks[64 * 64];         // [key][d] swizzled, 128B rows
    __shared__ u16 Vt[64 * 64];         // [d][key] swizzled
    __shared__ u16 Pw[4][2][16 * 64];   // per (wave, stream) P^T, swizzled

    const int t = threadIdx.x, w = t >> 6, lane = t & 63;
    const int l15 = lane & 15, quad = lane >> 4;
    const int id = blockIdx.x;
    const int kvh = id & 7;
    const int z = (id >> 3) & 1;
    const int gi = id >> 4;             // 0..63
    const int p = gi & 15;
    int g;
    switch (gi >> 4) {
        case 0:  g = 63 - p; break;
        case 1:  g = 32 + p; break;
        case 2:  g = 31 - p; break;
        default: g = p;      break;
    }
    const int h = kvh * 4 + w;
    const size_t rowbase = (size_t)z * 2048;
    const float SC = 0.125f * 1.4426950408889634f;  // 1/sqrt(64) * log2(e)
    const int swz = l15 & 7;

    const int srow = t >> 3;            // 0..31 (second row = srow+32)
    const int slot = t & 7;
    const int sd = slot << 3;
    const int lidx = srow * 64 + ((slot ^ (srow & 7)) << 3);

    const u16* kbase = &k[(rowbase + srow) * 512 + kvh * 64 + sd];
    const u16* vbase = &vT[(size_t)(kvh * 64 + srow) * 4096 + rowbase + sd];

    const int ntiles = (g >> 1) + 1;
    const int qrow0 = g * 32;

    bf16x8 aq[2][2];
#pragma unroll
    for (int m = 0; m < 2; ++m)
#pragma unroll
        for (int kc = 0; kc < 2; ++kc)
            aq[m][kc] = *(const bf16x8*)&q[(rowbase + qrow0 + m * 16 + l15) * 2048 +
                                           h * 64 + kc * 32 + quad * 8];

    f32x4 acc[2][4] = {};
    float m_i[2] = {-INFINITY, -INFINITY};
    float l_i[2] = {0.f, 0.f};

    u16x8 pk0 = *(const u16x8*)kbase;
    u16x8 pk1 = *(const u16x8*)(kbase + (size_t)32 * 512);
    u16x8 pv0 = *(const u16x8*)vbase;
    u16x8 pv1 = *(const u16x8*)(vbase + (size_t)32 * 4096);

    for (int kb = 0; kb < ntiles; ++kb) {
        __syncthreads();
        *(u16x8*)&Ks[lidx]        = pk0;
        *(u16x8*)&Ks[lidx + 2048] = pk1;
        *(u16x8*)&Vt[lidx]        = pv0;
        *(u16x8*)&Vt[lidx + 2048] = pv1;
        if (kb + 1 < ntiles) {
            const u16* kp = kbase + (size_t)(kb + 1) * 64 * 512;
            pk0 = *(const u16x8*)kp;
            pk1 = *(const u16x8*)(kp + (size_t)32 * 512);
            const u16* vp = vbase + (size_t)(kb + 1) * 64;
            pv0 = *(const u16x8*)vp;
            pv1 = *(const u16x8*)(vp + (size_t)32 * 4096);
        }
        __syncthreads();

        f32x4 st[2][4] = {};
        __builtin_amdgcn_s_setprio(1);
#pragma unroll
        for (int kt = 0; kt < 4; ++kt) {
            bf16x8 ak0 = *(const bf16x8*)&Ks[(kt * 16 + l15) * 64 + ((quad ^ swz) << 3)];
            bf16x8 ak1 = *(const bf16x8*)&Ks[(kt * 16 + l15) * 64 + (((quad + 4) ^ swz) << 3)];
#pragma unroll
            for (int m = 0; m < 2; ++m) {
                st[m][kt] = __builtin_amdgcn_mfma_f32_16x16x32_bf16(ak0, aq[m][0], st[m][kt], 0, 0, 0);
                st[m][kt] = __builtin_amdgcn_mfma_f32_16x16x32_bf16(ak1, aq[m][1], st[m][kt], 0, 0, 0);
            }
        }
        __builtin_amdgcn_s_setprio(0);

        const bool diag = (kb == ntiles - 1);
        float alpha_[2];
        bool resc[2];
#pragma unroll
        for (int m = 0; m < 2; ++m) {
            float sv[16];
#pragma unroll
            for (int kt = 0; kt < 4; ++kt)
#pragma unroll
                for (int r = 0; r < 4; ++r) sv[kt * 4 + r] = st[m][kt][r];
            if (diag) {
                const int qg = qrow0 + m * 16 + l15;
#pragma unroll
                for (int kt = 0; kt < 4; ++kt)
#pragma unroll
                    for (int r = 0; r < 4; ++r) {
                        int key = kb * 64 + kt * 16 + quad * 4 + r;
                        if (key > qg) sv[kt * 4 + r] = -INFINITY;
                    }
            }
            float mx = sv[0];
#pragma unroll
            for (int i = 1; i < 16; ++i) mx = fmaxf(mx, sv[i]);
            mx = fmaxf(mx, __shfl_xor(mx, 16));
            mx = fmaxf(mx, __shfl_xor(mx, 32));
            mx *= SC;
            const float mold = m_i[m];
            const bool need = __any(mx > mold + 8.f);
            float al = 1.f;
            if (need) {
                const float mnew = fmaxf(mold, mx);
                al = __builtin_amdgcn_exp2f(mold - mnew);
                m_i[m] = mnew;
            }
            const float mu = m_i[m];
            float sum = 0.f;
#pragma unroll
            for (int i = 0; i < 16; ++i) {
                sv[i] = __builtin_amdgcn_exp2f(fmaf(sv[i], SC, -mu));
                sum += sv[i];
            }
            sum += __shfl_xor(sum, 16);
            sum += __shfl_xor(sum, 32);
            l_i[m] = l_i[m] * al + sum;
            alpha_[m] = al;
            resc[m] = need;

            u16* Pq = &Pw[w][m][0];
#pragma unroll
            for (int kt = 0; kt < 4; ++kt) {
                uint2 uu;
                uu.x = cvtpk(sv[kt * 4 + 0], sv[kt * 4 + 1]);
                uu.y = cvtpk(sv[kt * 4 + 2], sv[kt * 4 + 3]);
                *(uint2*)&Pq[l15 * 64 + (((2 * kt + (quad >> 1)) ^ swz) << 3) + ((quad & 1) << 2)] = uu;
            }
        }

#pragma unroll
        for (int m = 0; m < 2; ++m)
            if (resc[m]) {
                const float al = alpha_[m];
#pragma unroll
                for (int dt = 0; dt < 4; ++dt)
#pragma unroll
                    for (int r = 0; r < 4; ++r) acc[m][dt][r] *= al;
            }

        bf16x8 bp[2][2];
#pragma unroll
        for (int m = 0; m < 2; ++m) {
            const u16* Pq = &Pw[w][m][0];
            bp[m][0] = *(const bf16x8*)&Pq[l15 * 64 + ((quad ^ swz) << 3)];
            bp[m][1] = *(const bf16x8*)&Pq[l15 * 64 + (((quad + 4) ^ swz) << 3)];
        }

        __builtin_amdgcn_s_setprio(1);
#pragma unroll
        for (int dt = 0; dt < 4; ++dt) {
            bf16x8 av0 = *(const bf16x8*)&Vt[(dt * 16 + l15) * 64 + ((quad ^ swz) << 3)];
            bf16x8 av1 = *(const bf16x8*)&Vt[(dt * 16 + l15) * 64 + (((quad + 4) ^ swz) << 3)];
#pragma unroll
            for (int m = 0; m < 2; ++m) {
                acc[m][dt] = __builtin_amdgcn_mfma_f32_16x16x32_bf16(av0, bp[m][0], acc[m][dt], 0, 0, 0);
                acc[m][dt] = __builtin_amdgcn_mfma_f32_16x16x32_bf16(av1, bp[m][1], acc[m][dt], 0, 0, 0);
            }
        }
        __builtin_amdgcn_s_setprio(0);
    }

#pragma unroll
    for (int m = 0; m < 2; ++m) {
        float inv = 1.0f / l_i[m];
        size_t row = rowbase + qrow0 + m * 16 + l15;
#pragma unroll
        for (int dt = 0; dt < 4; ++dt) {
            uint2 uu;
            uu.x = cvtpk(acc[m][dt][0] * inv, acc[m][dt][1] * inv);
            uu.y = cvtpk(acc[m][dt][2] * inv, acc[m][dt][3] * inv);
            *(uint2*)&att[row * 2048 + h * 64 + dt * 16 + quad * 4] = uu;
        }
    }
}

// ---------------------------------------------------------------------------
extern "C" void kernel_launch(void* const* d_in, const int* in_sizes, int n_in,
                              void* d_out, int out_size, void* d_ws, size_t ws_size,
                              hipStream_t stream) {
    const float* x  = (const float*)d_in[0];
    const float* Wq = (const float*)d_in[2];
    const float* Wk = (const float*)d_in[3];
    const float* Wv = (const float*)d_in[4];
    const float* Wo = (const float*)d_in[5];
    float* out = (float*)d_out;

    u16* xb = (u16*)d_out;                                   // bf16 x in d_out (dead before final write)

    u16* q     = (u16*)d_ws;                                 // 4096x2048
    u16* kk    = q + (size_t)4096 * 2048;                    // 4096x512
    u16* vt    = kk + (size_t)4096 * 512;                    // 512x4096 (V^T)
    u16* wqkvt = vt + (size_t)4096 * 512;                    // 3072x2048 (dead after QKV gemm)
    u16* att   = wqkvt;                                      // 4096x2048 aliases dead wqkvt
    u16* wot   = kk;                                         // 2048x2048 aliases dead kk+vt (after attn)

    cvt_x<<<4096, 256, 0, stream>>>(x, xb);
    tcvt3<<<dim3(96, 64), 256, 0, stream>>>(Wq, Wk, Wv, wqkvt);
    gemm8p<<<dim3(12, 16), 512, 0, stream>>>(xb, wqkvt, q, kk, vt);  // 8-phase QKV + rope
    attn8<<<1024, 256, 0, stream>>>(q, kk, vt, att);
    tcvt<<<dim3(64, 64), 256, 0, stream>>>(Wo, wot, 2048);
    gemm2<1><<<dim3(16, 32), 256, 0, stream>>>(att, wot, nullptr, nullptr, nullptr, out);
}

// Round 7
// 325.311 us; speedup vs baseline: 1.0164x; 1.0095x over previous
//
#include <hip/hip_runtime.h>
#include <cstdint>
#include <cstddef>

typedef unsigned short u16;
typedef __attribute__((ext_vector_type(8))) short bf16x8;
typedef __attribute__((ext_vector_type(8))) unsigned short u16x8;
typedef __attribute__((ext_vector_type(4))) unsigned short u16x4;
typedef __attribute__((ext_vector_type(4))) float f32x4;

__device__ __forceinline__ unsigned short f2bf(float f) {
    union { float f; uint32_t u; } c; c.f = f;
    uint32_t u = c.u + 0x7fffu + ((c.u >> 16) & 1u);
    return (unsigned short)(u >> 16);
}
__device__ __forceinline__ float bf2f(unsigned short h) {
    union { uint32_t u; float f; } c; c.u = ((uint32_t)h) << 16;
    return c.f;
}
// single-instruction pack: low16 = bf16(a), high16 = bf16(b)
__device__ __forceinline__ uint32_t cvtpk(float a, float b) {
    uint32_t r;
    asm("v_cvt_pk_bf16_f32 %0, %1, %2" : "=v"(r) : "v"(a), "v"(b));
    return r;
}

#define GLDS16(g, l)                                                               \
    __builtin_amdgcn_global_load_lds((const __attribute__((address_space(1))) void*)(g), \
                                     (__attribute__((address_space(3))) void*)(l), 16, 0, 0)

// ---------------------------------------------------------------------------
// fp32 -> bf16 straight convert (x).
// ---------------------------------------------------------------------------
__global__ __launch_bounds__(256) void cvt_x(const float* __restrict__ src,
                                             u16* __restrict__ dst) {
    int i = blockIdx.x * 256 + threadIdx.x;
    const float4* s = (const float4*)src + (size_t)i * 2;
    float4 a = s[0], b = s[1];
    u16x8 o;
    o[0] = f2bf(a.x); o[1] = f2bf(a.y); o[2] = f2bf(a.z); o[3] = f2bf(a.w);
    o[4] = f2bf(b.x); o[5] = f2bf(b.y); o[6] = f2bf(b.z); o[7] = f2bf(b.w);
    *(u16x8*)(dst + (size_t)i * 8) = o;
}

// ---------------------------------------------------------------------------
// Transpose-convert: src fp32 [2048 k][C n] -> dst bf16 [C n][2048 k].
// ---------------------------------------------------------------------------
__global__ __launch_bounds__(256) void tcvt(const float* __restrict__ src,
                                            u16* __restrict__ dst, int C) {
    __shared__ u16 tile[32][33];
    const int t = threadIdx.x;
    const int bx = blockIdx.x, by = blockIdx.y;
    const int tr = t >> 3, tc = (t & 7) << 2;
    float4 f = *(const float4*)&src[(size_t)(by * 32 + tr) * C + bx * 32 + tc];
    tile[tr][tc + 0] = f2bf(f.x); tile[tr][tc + 1] = f2bf(f.y);
    tile[tr][tc + 2] = f2bf(f.z); tile[tr][tc + 3] = f2bf(f.w);
    __syncthreads();
    u16x4 o;
    o[0] = tile[tc + 0][tr]; o[1] = tile[tc + 1][tr];
    o[2] = tile[tc + 2][tr]; o[3] = tile[tc + 3][tr];
    *(u16x4*)&dst[(size_t)(bx * 32 + tr) * 2048 + by * 32 + tc] = o;
}

// Merged transpose-convert for Wq|Wk|Wv -> wqkvt (one launch).
__global__ __launch_bounds__(256) void tcvt3(const float* __restrict__ Wq,
                                             const float* __restrict__ Wk,
                                             const float* __restrict__ Wv,
                                             u16* __restrict__ dst) {
    __shared__ u16 tile[32][33];
    const int t = threadIdx.x;
    const int bxg = blockIdx.x, by = blockIdx.y;
    const float* src; int C, nb; u16* dbase;
    if (bxg < 64)      { src = Wq; C = 2048; nb = bxg;      dbase = dst; }
    else if (bxg < 80) { src = Wk; C = 512;  nb = bxg - 64; dbase = dst + (size_t)2048 * 2048; }
    else               { src = Wv; C = 512;  nb = bxg - 80; dbase = dst + (size_t)2560 * 2048; }
    const int tr = t >> 3, tc = (t & 7) << 2;
    float4 f = *(const float4*)&src[(size_t)(by * 32 + tr) * C + nb * 32 + tc];
    tile[tr][tc + 0] = f2bf(f.x); tile[tr][tc + 1] = f2bf(f.y);
    tile[tr][tc + 2] = f2bf(f.z); tile[tr][tc + 3] = f2bf(f.w);
    __syncthreads();
    u16x4 o;
    o[0] = tile[tc + 0][tr]; o[1] = tile[tc + 1][tr];
    o[2] = tile[tc + 2][tr]; o[3] = tile[tc + 3][tr];
    *(u16x4*)&dbase[(size_t)(nb * 32 + tr) * 2048 + by * 32 + tc] = o;
}

// ---------------------------------------------------------------------------
// m97-style GEMM (kept for the output projection): C = A * Bt^T, MODE 1 only.
// ---------------------------------------------------------------------------
template <int MODE>
__global__ __launch_bounds__(256) void gemm2(const u16* __restrict__ A,
                                             const u16* __restrict__ Bt,
                                             u16* __restrict__ oq, u16* __restrict__ ok,
                                             u16* __restrict__ ov, float* __restrict__ of) {
    __shared__ u16 As[128 * 32];
    __shared__ u16 Bs[128 * 32];
    const int t = threadIdx.x, w = t >> 6, lane = t & 63;
    const int l15 = lane & 15, quad = lane >> 4;
    const int m0 = blockIdx.y << 7, n0 = blockIdx.x << 7;
    const int K = 2048;
    const int c0 = w * 2, c1 = c0 + 1;
    const int ar0 = c0 * 16 + (lane >> 2), ar1 = c1 * 16 + (lane >> 2);
    const int ac = (lane & 3) << 3;
    const u16* Ap0 = A + (size_t)(m0 + ar0) * K + ac;
    const u16* Ap1 = A + (size_t)(m0 + ar1) * K + ac;
    const u16* Bp0 = Bt + (size_t)(n0 + ar0) * K + ac;
    const u16* Bp1 = Bt + (size_t)(n0 + ar1) * K + ac;
    const int wm = (w >> 1) << 6, wn = (w & 1) << 6;

    f32x4 acc[4][4] = {};

    for (int k0 = 0; k0 < K; k0 += 32) {
        GLDS16(Ap0 + k0, &As[c0 * 512]);
        GLDS16(Ap1 + k0, &As[c1 * 512]);
        GLDS16(Bp0 + k0, &Bs[c0 * 512]);
        GLDS16(Bp1 + k0, &Bs[c1 * 512]);
        __syncthreads();
        bf16x8 a[4], bfr[4];
#pragma unroll
        for (int mt = 0; mt < 4; ++mt)
            a[mt] = *(bf16x8*)&As[(wm + mt * 16 + l15) * 32 + quad * 8];
#pragma unroll
        for (int nt = 0; nt < 4; ++nt)
            bfr[nt] = *(bf16x8*)&Bs[(wn + nt * 16 + l15) * 32 + quad * 8];
#pragma unroll
        for (int mt = 0; mt < 4; ++mt)
#pragma unroll
            for (int nt = 0; nt < 4; ++nt)
                acc[mt][nt] = __builtin_amdgcn_mfma_f32_16x16x32_bf16(a[mt], bfr[nt], acc[mt][nt], 0, 0, 0);
        __syncthreads();
    }

#pragma unroll
    for (int mt = 0; mt < 4; ++mt)
#pragma unroll
        for (int nt = 0; nt < 4; ++nt)
#pragma unroll
            for (int r = 0; r < 4; ++r) {
                int row = m0 + wm + mt * 16 + quad * 4 + r;
                int col = n0 + wn + nt * 16 + l15;
                of[(size_t)row * 2048 + col] = acc[mt][nt][r];
            }
}

// ---------------------------------------------------------------------------
// gemm8p v3: QKV projection, 256x256 tile, BK=64, 8 waves, 8-phase schedule.
// R7 change vs R6: M-quadrant phase decomposition (m201's actual "4 or 8
// ds_read per phase"). Per K-tile per wave: B read ONCE (8 x b128, held in
// regs across 4 phases), A read once per quadrant (4 x b128/phase) -> 24
// b128/K-tile (was 40: the (mq,nq) output-quadrant scheme re-read each
// A-quadrant twice). LDS-pipe cost/iter: 7680 -> 4608 cyc < MFMA 4966 cyc.
// Staging slots, counted vmcnt, barrier pairs, swizzle: unchanged (R5/R6
// verified: 0 bank conflicts, correct).
// ---------------------------------------------------------------------------
__global__ __launch_bounds__(512, 1) void gemm8p(const u16* __restrict__ A,
                                                 const u16* __restrict__ Bt,
                                                 u16* __restrict__ oq, u16* __restrict__ ok,
                                                 u16* __restrict__ ov) {
    __shared__ u16 lds[65536];   // 128 KB

    const int t = threadIdx.x, w = t >> 6, lane = t & 63;
    const int l15 = lane & 15, quad = lane >> 4;
    const int wm = w >> 2, wn = w & 3;
    const int m0 = blockIdx.y << 8, n0 = blockIdx.x << 8;
    const int K = 2048;
    const int NIT = 16;          // 32 K-tiles of 64, 2 per iteration

    // pre-swizzled per-lane stage source: row m0/n0 + w*8 + (lane>>3),
    // col-slot (lane&7)^(lane>>3)  [r&7 == lane>>3 for every staged row]
    const int srow = w * 8 + (lane >> 3);
    const int scol = ((lane & 7) ^ (lane >> 3)) << 3;
    const u16* pA = A + (size_t)(m0 + srow) * K + scol;
    const u16* pB = Bt + (size_t)(n0 + srow) * K + scol;

// stage one half-tile (128 rows x 64 cols): 2 global_load_lds per wave
#define STG(AB, BUF, HF, T) do {                                                   \
    const u16* _s = ((AB) ? pB : pA) + (size_t)((HF) * 128) * K + (size_t)(T) * 64; \
    u16* _d = &lds[(BUF) * 32768 + (AB) * 16384 + (HF) * 8192 + w * 512];          \
    GLDS16(_s, _d);                                                                \
    GLDS16(_s + (size_t)64 * K, _d + 4096);                                        \
} while (0)

// A quadrant (MQ in 0..3): 2 M-frags x 2 k-slices = 4 x ds_read_b128
#define RD_A2(BUF, MQ)                                                             \
    _Pragma("unroll") for (int fi = 0; fi < 2; ++fi)                               \
    _Pragma("unroll") for (int ks = 0; ks < 2; ++ks) {                             \
        int r_ = (MQ) * 32 + fi * 16 + l15;                                        \
        int u_ = ks * 4 + quad;                                                    \
        a_[fi][ks] = *(const bf16x8*)&lds[(BUF) * 32768 + wm * 8192 + r_ * 64 +    \
                                          ((u_ ^ (r_ & 7)) << 3)];                 \
    }
// full B for the K-tile: 4 N-frags x 2 k-slices = 8 x ds_read_b128
#define RD_B8(BUF)                                                                 \
    _Pragma("unroll") for (int fj = 0; fj < 4; ++fj)                               \
    _Pragma("unroll") for (int ks = 0; ks < 2; ++ks) {                             \
        int r_ = (wn & 1) * 64 + fj * 16 + l15;                                    \
        int u_ = ks * 4 + quad;                                                    \
        b_[fj][ks] = *(const bf16x8*)&lds[(BUF) * 32768 + 16384 + (wn >> 1) * 8192 \
                                          + r_ * 64 + ((u_ ^ (r_ & 7)) << 3)];     \
    }
// 16 MFMA: 2 M-frags x 4 N-frags x 2 k-slices
#define MFMA16Q(MQ)                                                                \
    __builtin_amdgcn_s_barrier();                                                  \
    __builtin_amdgcn_s_setprio(1);                                                 \
    _Pragma("unroll") for (int fi = 0; fi < 2; ++fi)                               \
    _Pragma("unroll") for (int fj = 0; fj < 4; ++fj) {                             \
        acc[(MQ) * 2 + fi][fj] = __builtin_amdgcn_mfma_f32_16x16x32_bf16(          \
            a_[fi][0], b_[fj][0], acc[(MQ) * 2 + fi][fj], 0, 0, 0);                \
        acc[(MQ) * 2 + fi][fj] = __builtin_amdgcn_mfma_f32_16x16x32_bf16(          \
            a_[fi][1], b_[fj][1], acc[(MQ) * 2 + fi][fj], 0, 0, 0);                \
    }                                                                              \
    __builtin_amdgcn_s_setprio(0);

    f32x4 acc[8][4] = {};
    bf16x8 a_[2][2], b_[4][2];

    // prologue: tile0 A0,A1,B0,B1 -> buf0; tile1 B0,B1 -> buf1 (12 loads)
    STG(0, 0, 0, 0); STG(0, 0, 1, 0);
    STG(1, 0, 0, 0); STG(1, 0, 1, 0);
    STG(1, 1, 0, 1); STG(1, 1, 1, 1);
    asm volatile("s_waitcnt vmcnt(4)" ::: "memory");   // tile0 landed
    __builtin_amdgcn_s_barrier();

    for (int it = 0; it < NIT; ++it) {
        const bool more = (it + 1 < NIT);
        const int o = 2 * it + 1, e2 = 2 * it + 2, o2 = 2 * it + 3;

        // ph1: buf0 mq0 (+ full B read); stage A0(odd) -> buf1
        RD_B8(0); RD_A2(0, 0);
        STG(0, 1, 0, o);
        MFMA16Q(0);
        __builtin_amdgcn_s_barrier();

        // ph2: buf0 mq1; stage A1(odd) -> buf1
        RD_A2(0, 1);
        STG(0, 1, 1, o);
        MFMA16Q(1);
        __builtin_amdgcn_s_barrier();

        // ph3: buf0 mq2
        RD_A2(0, 2);
        MFMA16Q(2);
        __builtin_amdgcn_s_barrier();

        // ph4: buf0 mq3; stage B0,B1(even+2) -> buf0; vmcnt
        RD_A2(0, 3);
        if (more) { STG(1, 0, 0, e2); STG(1, 0, 1, e2); }
        MFMA16Q(3);
        if (more) asm volatile("s_waitcnt vmcnt(4)" ::: "memory");
        else      asm volatile("s_waitcnt vmcnt(0)" ::: "memory");
        __builtin_amdgcn_s_barrier();

        // ph5: buf1 mq0 (+ full B read); stage A0(even+2) -> buf0
        RD_B8(1); RD_A2(1, 0);
        if (more) STG(0, 0, 0, e2);
        MFMA16Q(0);
        __builtin_amdgcn_s_barrier();

        // ph6: buf1 mq1; stage A1(even+2) -> buf0
        RD_A2(1, 1);
        if (more) STG(0, 0, 1, e2);
        MFMA16Q(1);
        __builtin_amdgcn_s_barrier();

        // ph7: buf1 mq2
        RD_A2(1, 2);
        MFMA16Q(2);
        __builtin_amdgcn_s_barrier();

        // ph8: buf1 mq3; stage B0,B1(odd+2) -> buf1; vmcnt
        RD_A2(1, 3);
        if (more) { STG(1, 1, 0, o2); STG(1, 1, 1, o2); }
        MFMA16Q(3);
        if (more) asm volatile("s_waitcnt vmcnt(4)" ::: "memory");
        else      asm volatile("s_waitcnt vmcnt(0)" ::: "memory");
        __builtin_amdgcn_s_barrier();
    }
#undef STG
#undef RD_A2
#undef RD_B8
#undef MFMA16Q

    // ---------------- epilogue: RoPE (Q,K) / V^T, same layout as before ----
    const int colbase = n0 + wn * 64;
    const bool isv = (colbase >= 2560);
    float iv[4];
    if (!isv) {
#pragma unroll
        for (int nj = 0; nj < 4; ++nj)
            iv[nj] = exp2f(-0.4152410118609253f * (float)(nj * 8 + (l15 >> 1)));
    }
    const int map1 = (quad << 4) | ((2 * l15 + 1) & 15);  // odd partners (d<32)
    const int map2 = (quad << 4) | ((2 * l15) & 15);      // even partners (d>=32)
    const bool lo = (l15 < 8);
#pragma unroll
    for (int mi = 0; mi < 8; ++mi)
#pragma unroll
        for (int r = 0; r < 4; ++r) {
            const int row = m0 + wm * 128 + mi * 16 + quad * 4 + r;
            float v0 = acc[mi][0][r], v1 = acc[mi][1][r];
            float v2 = acc[mi][2][r], v3 = acc[mi][3][r];
            float o0 = v0, o1 = v1, o2 = v2, o3 = v3;
            if (!isv) {
                float g1a = __shfl(v0, map1), g1b = __shfl(v1, map1);
                float g1c = __shfl(v2, map1), g1d = __shfl(v3, map1);
                float g2a = __shfl(v0, map2), g2b = __shfl(v1, map2);
                float g2c = __shfl(v2, map2), g2d = __shfl(v3, map2);
                float p0 = lo ? g1a : g1b;
                float p1 = lo ? g1c : g1d;
                float p2 = lo ? g2a : g2b;
                float p3 = lo ? g2c : g2d;
                const float tt = (float)(row & 2047);
                float sn, cs;
                __sincosf(tt * iv[0], &sn, &cs); o0 = v0 * cs - p0 * sn;
                __sincosf(tt * iv[1], &sn, &cs); o1 = v1 * cs - p1 * sn;
                __sincosf(tt * iv[2], &sn, &cs); o2 = v2 * cs + p2 * sn;
                __sincosf(tt * iv[3], &sn, &cs); o3 = v3 * cs + p3 * sn;
            }
            float oo[4] = {o0, o1, o2, o3};
            if (colbase < 2048) {
#pragma unroll
                for (int nj = 0; nj < 4; ++nj)
                    oq[(size_t)row * 2048 + colbase + nj * 16 + l15] = f2bf(oo[nj]);
            } else if (colbase < 2560) {
#pragma unroll
                for (int nj = 0; nj < 4; ++nj)
                    ok[(size_t)row * 512 + colbase - 2048 + nj * 16 + l15] = f2bf(oo[nj]);
            } else {
#pragma unroll
                for (int nj = 0; nj < 4; ++nj)
                    ov[(size_t)(colbase - 2560 + nj * 16 + l15) * 4096 + row] = f2bf(oo[nj]);
            }
        }
}

// ---------------------------------------------------------------------------
// Flash attention v8 (R4, verified 310.8us config) — unchanged.
// launch_bounds(256,2): VGPR cap 128, kernel needs ~120, no spill.
// ---------------------------------------------------------------------------
__global__ __launch_bounds__(256, 2) void attn8(const u16* __restrict__ q,
                                                const u16* __restrict__ k,
                                                const u16* __restrict__ vT,
                                                u16* __restrict__ att) {
    __shared__ u16 Ks[64 * 64];         // [key][d] swizzled, 128B rows
    __shared__ u16 Vt[64 * 64];         // [d][key] swizzled
    __shared__ u16 Pw[4][2][16 * 64];   // per (wave, stream) P^T, swizzled

    const int t = threadIdx.x, w = t >> 6, lane = t & 63;
    const int l15 = lane & 15, quad = lane >> 4;
    const int id = blockIdx.x;
    const int kvh = id & 7;
    const int z = (id >> 3) & 1;
    const int gi = id >> 4;             // 0..63
    const int p = gi & 15;
    int g;
    switch (gi >> 4) {
        case 0:  g = 63 - p; break;
        case 1:  g = 32 + p; break;
        case 2:  g = 31 - p; break;
        default: g = p;      break;
    }
    const int h = kvh * 4 + w;
    const size_t rowbase = (size_t)z * 2048;
    const float SC = 0.125f * 1.4426950408889634f;  // 1/sqrt(64) * log2(e)
    const int swz = l15 & 7;

    const int srow = t >> 3;            // 0..31 (second row = srow+32)
    const int slot = t & 7;
    const int sd = slot << 3;
    const int lidx = srow * 64 + ((slot ^ (srow & 7)) << 3);

    const u16* kbase = &k[(rowbase + srow) * 512 + kvh * 64 + sd];
    const u16* vbase = &vT[(size_t)(kvh * 64 + srow) * 4096 + rowbase + sd];

    const int ntiles = (g >> 1) + 1;
    const int qrow0 = g * 32;

    bf16x8 aq[2][2];
#pragma unroll
    for (int m = 0; m < 2; ++m)
#pragma unroll
        for (int kc = 0; kc < 2; ++kc)
            aq[m][kc] = *(const bf16x8*)&q[(rowbase + qrow0 + m * 16 + l15) * 2048 +
                                           h * 64 + kc * 32 + quad * 8];

    f32x4 acc[2][4] = {};
    float m_i[2] = {-INFINITY, -INFINITY};
    float l_i[2] = {0.f, 0.f};

    u16x8 pk0 = *(const u16x8*)kbase;
    u16x8 pk1 = *(const u16x8*)(kbase + (size_t)32 * 512);
    u16x8 pv0 = *(const u16x8*)vbase;
    u16x8 pv1 = *(const u16x8*)(vbase + (size_t)32 * 4096);

    for (int kb = 0; kb < ntiles; ++kb) {
        __syncthreads();
        *(u16x8*)&Ks[lidx]        = pk0;
        *(u16x8*)&Ks[lidx + 2048] = pk1;
        *(u16x8*)&Vt[lidx]        = pv0;
        *(u16x8*)&Vt[lidx + 2048] = pv1;
        if (kb + 1 < ntiles) {
            const u16* kp = kbase + (size_t)(kb + 1) * 64 * 512;
            pk0 = *(const u16x8*)kp;
            pk1 = *(const u16x8*)(kp + (size_t)32 * 512);
            const u16* vp = vbase + (size_t)(kb + 1) * 64;
            pv0 = *(const u16x8*)vp;
            pv1 = *(const u16x8*)(vp + (size_t)32 * 4096);
        }
        __syncthreads();

        f32x4 st[2][4] = {};
        __builtin_amdgcn_s_setprio(1);
#pragma unroll
        for (int kt = 0; kt < 4; ++kt) {
            bf16x8 ak0 = *(const bf16x8*)&Ks[(kt * 16 + l15) * 64 + ((quad ^ swz) << 3)];
            bf16x8 ak1 = *(const bf16x8*)&Ks[(kt * 16 + l15) * 64 + (((quad + 4) ^ swz) << 3)];
#pragma unroll
            for (int m = 0; m < 2; ++m) {
                st[m][kt] = __builtin_amdgcn_mfma_f32_16x16x32_bf16(ak0, aq[m][0], st[m][kt], 0, 0, 0);
                st[m][kt] = __builtin_amdgcn_mfma_f32_16x16x32_bf16(ak1, aq[m][1], st[m][kt], 0, 0, 0);
            }
        }
        __builtin_amdgcn_s_setprio(0);

        const bool diag = (kb == ntiles - 1);
        float alpha_[2];
        bool resc[2];
#pragma unroll
        for (int m = 0; m < 2; ++m) {
            float sv[16];
#pragma unroll
            for (int kt = 0; kt < 4; ++kt)
#pragma unroll
                for (int r = 0; r < 4; ++r) sv[kt * 4 + r] = st[m][kt][r];
            if (diag) {
                const int qg = qrow0 + m * 16 + l15;
#pragma unroll
                for (int kt = 0; kt < 4; ++kt)
#pragma unroll
                    for (int r = 0; r < 4; ++r) {
                        int key = kb * 64 + kt * 16 + quad * 4 + r;
                        if (key > qg) sv[kt * 4 + r] = -INFINITY;
                    }
            }
            float mx = sv[0];
#pragma unroll
            for (int i = 1; i < 16; ++i) mx = fmaxf(mx, sv[i]);
            mx = fmaxf(mx, __shfl_xor(mx, 16));
            mx = fmaxf(mx, __shfl_xor(mx, 32));
            mx *= SC;
            const float mold = m_i[m];
            const bool need = __any(mx > mold + 8.f);
            float al = 1.f;
            if (need) {
                const float mnew = fmaxf(mold, mx);
                al = __builtin_amdgcn_exp2f(mold - mnew);
                m_i[m] = mnew;
            }
            const float mu = m_i[m];
            float sum = 0.f;
#pragma unroll
            for (int i = 0; i < 16; ++i) {
                sv[i] = __builtin_amdgcn_exp2f(fmaf(sv[i], SC, -mu));
                sum += sv[i];
            }
            sum += __shfl_xor(sum, 16);
            sum += __shfl_xor(sum, 32);
            l_i[m] = l_i[m] * al + sum;
            alpha_[m] = al;
            resc[m] = need;

            u16* Pq = &Pw[w][m][0];
#pragma unroll
            for (int kt = 0; kt < 4; ++kt) {
                uint2 uu;
                uu.x = cvtpk(sv[kt * 4 + 0], sv[kt * 4 + 1]);
                uu.y = cvtpk(sv[kt * 4 + 2], sv[kt * 4 + 3]);
                *(uint2*)&Pq[l15 * 64 + (((2 * kt + (quad >> 1)) ^ swz) << 3) + ((quad & 1) << 2)] = uu;
            }
        }

#pragma unroll
        for (int m = 0; m < 2; ++m)
            if (resc[m]) {
                const float al = alpha_[m];
#pragma unroll
                for (int dt = 0; dt < 4; ++dt)
#pragma unroll
                    for (int r = 0; r < 4; ++r) acc[m][dt][r] *= al;
            }

        bf16x8 bp[2][2];
#pragma unroll
        for (int m = 0; m < 2; ++m) {
            const u16* Pq = &Pw[w][m][0];
            bp[m][0] = *(const bf16x8*)&Pq[l15 * 64 + ((quad ^ swz) << 3)];
            bp[m][1] = *(const bf16x8*)&Pq[l15 * 64 + (((quad + 4) ^ swz) << 3)];
        }

        __builtin_amdgcn_s_setprio(1);
#pragma unroll
        for (int dt = 0; dt < 4; ++dt) {
            bf16x8 av0 = *(const bf16x8*)&Vt[(dt * 16 + l15) * 64 + ((quad ^ swz) << 3)];
            bf16x8 av1 = *(const bf16x8*)&Vt[(dt * 16 + l15) * 64 + (((quad + 4) ^ swz) << 3)];
#pragma unroll
            for (int m = 0; m < 2; ++m) {
                acc[m][dt] = __builtin_amdgcn_mfma_f32_16x16x32_bf16(av0, bp[m][0], acc[m][dt], 0, 0, 0);
                acc[m][dt] = __builtin_amdgcn_mfma_f32_16x16x32_bf16(av1, bp[m][1], acc[m][dt], 0, 0, 0);
            }
        }
        __builtin_amdgcn_s_setprio(0);
    }

#pragma unroll
    for (int m = 0; m < 2; ++m) {
        float inv = 1.0f / l_i[m];
        size_t row = rowbase + qrow0 + m * 16 + l15;
#pragma unroll
        for (int dt = 0; dt < 4; ++dt) {
            uint2 uu;
            uu.x = cvtpk(acc[m][dt][0] * inv, acc[m][dt][1] * inv);
            uu.y = cvtpk(acc[m][dt][2] * inv, acc[m][dt][3] * inv);
            *(uint2*)&att[row * 2048 + h * 64 + dt * 16 + quad * 4] = uu;
        }
    }
}

// ---------------------------------------------------------------------------
extern "C" void kernel_launch(void* const* d_in, const int* in_sizes, int n_in,
                              void* d_out, int out_size, void* d_ws, size_t ws_size,
                              hipStream_t stream) {
    const float* x  = (const float*)d_in[0];
    const float* Wq = (const float*)d_in[2];
    const float* Wk = (const float*)d_in[3];
    const float* Wv = (const float*)d_in[4];
    const float* Wo = (const float*)d_in[5];
    float* out = (float*)d_out;

    u16* xb = (u16*)d_out;                                   // bf16 x in d_out (dead before final write)

    u16* q     = (u16*)d_ws;                                 // 4096x2048
    u16* kk    = q + (size_t)4096 * 2048;                    // 4096x512
    u16* vt    = kk + (size_t)4096 * 512;                    // 512x4096 (V^T)
    u16* wqkvt = vt + (size_t)4096 * 512;                    // 3072x2048 (dead after QKV gemm)
    u16* att   = wqkvt;                                      // 4096x2048 aliases dead wqkvt
    u16* wot   = kk;                                         // 2048x2048 aliases dead kk+vt (after attn)

    cvt_x<<<4096, 256, 0, stream>>>(x, xb);
    tcvt3<<<dim3(96, 64), 256, 0, stream>>>(Wq, Wk, Wv, wqkvt);
    gemm8p<<<dim3(12, 16), 512, 0, stream>>>(xb, wqkvt, q, kk, vt);  // 8-phase QKV + rope
    attn8<<<1024, 256, 0, stream>>>(q, kk, vt, att);
    tcvt<<<dim3(64, 64), 256, 0, stream>>>(Wo, wot, 2048);
    gemm2<1><<<dim3(16, 32), 256, 0, stream>>>(att, wot, nullptr, nullptr, nullptr, out);
}

// Round 8
// 312.413 us; speedup vs baseline: 1.0584x; 1.0413x over previous
//
#include <hip/hip_runtime.h>
#include <cstdint>
#include <cstddef>

typedef unsigned short u16;
typedef __attribute__((ext_vector_type(8))) short bf16x8;
typedef __attribute__((ext_vector_type(8))) unsigned short u16x8;
typedef __attribute__((ext_vector_type(4))) unsigned short u16x4;
typedef __attribute__((ext_vector_type(4))) float f32x4;

__device__ __forceinline__ unsigned short f2bf(float f) {
    union { float f; uint32_t u; } c; c.f = f;
    uint32_t u = c.u + 0x7fffu + ((c.u >> 16) & 1u);
    return (unsigned short)(u >> 16);
}
__device__ __forceinline__ float bf2f(unsigned short h) {
    union { uint32_t u; float f; } c; c.u = ((uint32_t)h) << 16;
    return c.f;
}
// single-instruction pack: low16 = bf16(a), high16 = bf16(b)
__device__ __forceinline__ uint32_t cvtpk(float a, float b) {
    uint32_t r;
    asm("v_cvt_pk_bf16_f32 %0, %1, %2" : "=v"(r) : "v"(a), "v"(b));
    return r;
}

#define GLDS16(g, l)                                                               \
    __builtin_amdgcn_global_load_lds((const __attribute__((address_space(1))) void*)(g), \
                                     (__attribute__((address_space(3))) void*)(l), 16, 0, 0)

// ---------------------------------------------------------------------------
// fp32 -> bf16 straight convert (x).
// ---------------------------------------------------------------------------
__global__ __launch_bounds__(256) void cvt_x(const float* __restrict__ src,
                                             u16* __restrict__ dst) {
    int i = blockIdx.x * 256 + threadIdx.x;
    const float4* s = (const float4*)src + (size_t)i * 2;
    float4 a = s[0], b = s[1];
    u16x8 o;
    o[0] = f2bf(a.x); o[1] = f2bf(a.y); o[2] = f2bf(a.z); o[3] = f2bf(a.w);
    o[4] = f2bf(b.x); o[5] = f2bf(b.y); o[6] = f2bf(b.z); o[7] = f2bf(b.w);
    *(u16x8*)(dst + (size_t)i * 8) = o;
}

// ---------------------------------------------------------------------------
// Transpose-convert: src fp32 [2048 k][C n] -> dst bf16 [C n][2048 k].
// ---------------------------------------------------------------------------
__global__ __launch_bounds__(256) void tcvt(const float* __restrict__ src,
                                            u16* __restrict__ dst, int C) {
    __shared__ u16 tile[32][33];
    const int t = threadIdx.x;
    const int bx = blockIdx.x, by = blockIdx.y;
    const int tr = t >> 3, tc = (t & 7) << 2;
    float4 f = *(const float4*)&src[(size_t)(by * 32 + tr) * C + bx * 32 + tc];
    tile[tr][tc + 0] = f2bf(f.x); tile[tr][tc + 1] = f2bf(f.y);
    tile[tr][tc + 2] = f2bf(f.z); tile[tr][tc + 3] = f2bf(f.w);
    __syncthreads();
    u16x4 o;
    o[0] = tile[tc + 0][tr]; o[1] = tile[tc + 1][tr];
    o[2] = tile[tc + 2][tr]; o[3] = tile[tc + 3][tr];
    *(u16x4*)&dst[(size_t)(bx * 32 + tr) * 2048 + by * 32 + tc] = o;
}

// Merged transpose-convert for Wq|Wk|Wv -> wqkvt (one launch).
__global__ __launch_bounds__(256) void tcvt3(const float* __restrict__ Wq,
                                             const float* __restrict__ Wk,
                                             const float* __restrict__ Wv,
                                             u16* __restrict__ dst) {
    __shared__ u16 tile[32][33];
    const int t = threadIdx.x;
    const int bxg = blockIdx.x, by = blockIdx.y;
    const float* src; int C, nb; u16* dbase;
    if (bxg < 64)      { src = Wq; C = 2048; nb = bxg;      dbase = dst; }
    else if (bxg < 80) { src = Wk; C = 512;  nb = bxg - 64; dbase = dst + (size_t)2048 * 2048; }
    else               { src = Wv; C = 512;  nb = bxg - 80; dbase = dst + (size_t)2560 * 2048; }
    const int tr = t >> 3, tc = (t & 7) << 2;
    float4 f = *(const float4*)&src[(size_t)(by * 32 + tr) * C + nb * 32 + tc];
    tile[tr][tc + 0] = f2bf(f.x); tile[tr][tc + 1] = f2bf(f.y);
    tile[tr][tc + 2] = f2bf(f.z); tile[tr][tc + 3] = f2bf(f.w);
    __syncthreads();
    u16x4 o;
    o[0] = tile[tc + 0][tr]; o[1] = tile[tc + 1][tr];
    o[2] = tile[tc + 2][tr]; o[3] = tile[tc + 3][tr];
    *(u16x4*)&dbase[(size_t)(nb * 32 + tr) * 2048 + by * 32 + tc] = o;
}

// ---------------------------------------------------------------------------
// m97-style GEMM: C[M x N] = A[M x 2048] * Bt[N x 2048]^T, bf16 inputs.
// MODE 0: segmented qkv epilogue with FUSED ROPE (q,k roped; v transposed).
// MODE 1: fp32 C, N=2048.
// R8 note: 8-phase 256^2 port (R5-R7) peaked at 85.6us vs this kernel's 77.7:
// at M=4096 x N=3072 the 256^2 grid is 192 blocks = 75% CU fill, and
// 0.75 x (8-phase ~848 TF, m248) < 663 TF this 2-phase structure measures.
// Reverted per pre-commitment.
// ---------------------------------------------------------------------------
template <int MODE>
__global__ __launch_bounds__(256) void gemm2(const u16* __restrict__ A,
                                             const u16* __restrict__ Bt,
                                             u16* __restrict__ oq, u16* __restrict__ ok,
                                             u16* __restrict__ ov, float* __restrict__ of) {
    __shared__ u16 As[128 * 32];
    __shared__ u16 Bs[128 * 32];
    const int t = threadIdx.x, w = t >> 6, lane = t & 63;
    const int l15 = lane & 15, quad = lane >> 4;
    const int m0 = blockIdx.y << 7, n0 = blockIdx.x << 7;
    const int K = 2048;
    const int c0 = w * 2, c1 = c0 + 1;
    const int ar0 = c0 * 16 + (lane >> 2), ar1 = c1 * 16 + (lane >> 2);
    const int ac = (lane & 3) << 3;
    const u16* Ap0 = A + (size_t)(m0 + ar0) * K + ac;
    const u16* Ap1 = A + (size_t)(m0 + ar1) * K + ac;
    const u16* Bp0 = Bt + (size_t)(n0 + ar0) * K + ac;
    const u16* Bp1 = Bt + (size_t)(n0 + ar1) * K + ac;
    const int wm = (w >> 1) << 6, wn = (w & 1) << 6;

    f32x4 acc[4][4] = {};

    for (int k0 = 0; k0 < K; k0 += 32) {
        GLDS16(Ap0 + k0, &As[c0 * 512]);
        GLDS16(Ap1 + k0, &As[c1 * 512]);
        GLDS16(Bp0 + k0, &Bs[c0 * 512]);
        GLDS16(Bp1 + k0, &Bs[c1 * 512]);
        __syncthreads();
        bf16x8 a[4], bfr[4];
#pragma unroll
        for (int mt = 0; mt < 4; ++mt)
            a[mt] = *(bf16x8*)&As[(wm + mt * 16 + l15) * 32 + quad * 8];
#pragma unroll
        for (int nt = 0; nt < 4; ++nt)
            bfr[nt] = *(bf16x8*)&Bs[(wn + nt * 16 + l15) * 32 + quad * 8];
#pragma unroll
        for (int mt = 0; mt < 4; ++mt)
#pragma unroll
            for (int nt = 0; nt < 4; ++nt)
                acc[mt][nt] = __builtin_amdgcn_mfma_f32_16x16x32_bf16(a[mt], bfr[nt], acc[mt][nt], 0, 0, 0);
        __syncthreads();
    }

    if constexpr (MODE == 0) {
        // Wave's 64-col span (wn) is exactly one head. RoPE for Q/K heads:
        // d = nt*16+l15 in [0,64); d<32: out = x[d]c - x[2d+1]s ; d>=32: out = x[d]c + x[2(d-32)]s.
        const int colbase = n0 + wn;
        const bool isv = (colbase >= 2560);
        float iv[4];
        if (!isv) {
#pragma unroll
            for (int nt = 0; nt < 4; ++nt)
                iv[nt] = exp2f(-0.4152410118609253f * (float)(nt * 8 + (l15 >> 1)));
        }
        const int map1 = (quad << 4) | ((2 * l15 + 1) & 15);  // odd partners (d<32)
        const int map2 = (quad << 4) | ((2 * l15) & 15);      // even partners (d>=32)
        const bool lo = (l15 < 8);
#pragma unroll
        for (int mt = 0; mt < 4; ++mt)
#pragma unroll
            for (int r = 0; r < 4; ++r) {
                const int row = m0 + wm + mt * 16 + quad * 4 + r;
                float v0 = acc[mt][0][r], v1 = acc[mt][1][r];
                float v2 = acc[mt][2][r], v3 = acc[mt][3][r];
                float o0 = v0, o1 = v1, o2 = v2, o3 = v3;
                if (!isv) {
                    float g1a = __shfl(v0, map1), g1b = __shfl(v1, map1);
                    float g1c = __shfl(v2, map1), g1d = __shfl(v3, map1);
                    float g2a = __shfl(v0, map2), g2b = __shfl(v1, map2);
                    float g2c = __shfl(v2, map2), g2d = __shfl(v3, map2);
                    float p0 = lo ? g1a : g1b;   // x[2d+1] for nt=0
                    float p1 = lo ? g1c : g1d;   // x[2d+1] for nt=1
                    float p2 = lo ? g2a : g2b;   // x[2(d-32)] for nt=2
                    float p3 = lo ? g2c : g2d;   // x[2(d-32)] for nt=3
                    const float tt = (float)(row & 2047);
                    float sn, cs;
                    __sincosf(tt * iv[0], &sn, &cs); o0 = v0 * cs - p0 * sn;
                    __sincosf(tt * iv[1], &sn, &cs); o1 = v1 * cs - p1 * sn;
                    __sincosf(tt * iv[2], &sn, &cs); o2 = v2 * cs + p2 * sn;
                    __sincosf(tt * iv[3], &sn, &cs); o3 = v3 * cs + p3 * sn;
                }
                float o[4] = {o0, o1, o2, o3};
                if (colbase < 2048) {
#pragma unroll
                    for (int nt = 0; nt < 4; ++nt)
                        oq[(size_t)row * 2048 + colbase + nt * 16 + l15] = f2bf(o[nt]);
                } else if (colbase < 2560) {
#pragma unroll
                    for (int nt = 0; nt < 4; ++nt)
                        ok[(size_t)row * 512 + colbase - 2048 + nt * 16 + l15] = f2bf(o[nt]);
                } else {
#pragma unroll
                    for (int nt = 0; nt < 4; ++nt)
                        ov[(size_t)(colbase - 2560 + nt * 16 + l15) * 4096 + row] = f2bf(o[nt]);
                }
            }
    } else {
#pragma unroll
        for (int mt = 0; mt < 4; ++mt)
#pragma unroll
            for (int nt = 0; nt < 4; ++nt)
#pragma unroll
                for (int r = 0; r < 4; ++r) {
                    int row = m0 + wm + mt * 16 + quad * 4 + r;
                    int col = n0 + wn + nt * 16 + l15;
                    of[(size_t)row * 2048 + col] = acc[mt][nt][r];
                }
    }
}

// ---------------------------------------------------------------------------
// Flash attention v8 (R4, verified 310.8us config).
// Block = one 32-row Q-group x 4 heads (4 waves, 256 thr). Grid flat 1024:
// id -> kvh = id&7, z = (id>>3)&1, gi = id>>4; g mapped {63-p,32+p,31-p,p}
// so the 4 co-resident blocks per CU have constant total tile count (65).
// LDS 32KB (swizzled stride-64 K/V single-buffer + per-wave P).
// launch_bounds(256,2): hipcc VGPR cap = 256/N -> 128 regs; kernel needs ~120,
// NO spill. (·,4) capped at 64 regs and spilled ~140MB: R2/R3 lesson.
// ---------------------------------------------------------------------------
__global__ __launch_bounds__(256, 2) void attn8(const u16* __restrict__ q,
                                                const u16* __restrict__ k,
                                                const u16* __restrict__ vT,
                                                u16* __restrict__ att) {
    __shared__ u16 Ks[64 * 64];         // [key][d] swizzled, 128B rows
    __shared__ u16 Vt[64 * 64];         // [d][key] swizzled
    __shared__ u16 Pw[4][2][16 * 64];   // per (wave, stream) P^T, swizzled

    const int t = threadIdx.x, w = t >> 6, lane = t & 63;
    const int l15 = lane & 15, quad = lane >> 4;
    const int id = blockIdx.x;
    const int kvh = id & 7;
    const int z = (id >> 3) & 1;
    const int gi = id >> 4;             // 0..63
    const int p = gi & 15;
    int g;
    switch (gi >> 4) {
        case 0:  g = 63 - p; break;
        case 1:  g = 32 + p; break;
        case 2:  g = 31 - p; break;
        default: g = p;      break;
    }
    const int h = kvh * 4 + w;
    const size_t rowbase = (size_t)z * 2048;
    const float SC = 0.125f * 1.4426950408889634f;  // 1/sqrt(64) * log2(e)
    const int swz = l15 & 7;

    const int srow = t >> 3;            // 0..31 (second row = srow+32)
    const int slot = t & 7;
    const int sd = slot << 3;
    const int lidx = srow * 64 + ((slot ^ (srow & 7)) << 3);

    const u16* kbase = &k[(rowbase + srow) * 512 + kvh * 64 + sd];
    const u16* vbase = &vT[(size_t)(kvh * 64 + srow) * 4096 + rowbase + sd];

    const int ntiles = (g >> 1) + 1;
    const int qrow0 = g * 32;

    bf16x8 aq[2][2];
#pragma unroll
    for (int m = 0; m < 2; ++m)
#pragma unroll
        for (int kc = 0; kc < 2; ++kc)
            aq[m][kc] = *(const bf16x8*)&q[(rowbase + qrow0 + m * 16 + l15) * 2048 +
                                           h * 64 + kc * 32 + quad * 8];

    f32x4 acc[2][4] = {};
    float m_i[2] = {-INFINITY, -INFINITY};
    float l_i[2] = {0.f, 0.f};

    u16x8 pk0 = *(const u16x8*)kbase;
    u16x8 pk1 = *(const u16x8*)(kbase + (size_t)32 * 512);
    u16x8 pv0 = *(const u16x8*)vbase;
    u16x8 pv1 = *(const u16x8*)(vbase + (size_t)32 * 4096);

    for (int kb = 0; kb < ntiles; ++kb) {
        __syncthreads();
        *(u16x8*)&Ks[lidx]        = pk0;
        *(u16x8*)&Ks[lidx + 2048] = pk1;
        *(u16x8*)&Vt[lidx]        = pv0;
        *(u16x8*)&Vt[lidx + 2048] = pv1;
        if (kb + 1 < ntiles) {
            const u16* kp = kbase + (size_t)(kb + 1) * 64 * 512;
            pk0 = *(const u16x8*)kp;
            pk1 = *(const u16x8*)(kp + (size_t)32 * 512);
            const u16* vp = vbase + (size_t)(kb + 1) * 64;
            pv0 = *(const u16x8*)vp;
            pv1 = *(const u16x8*)(vp + (size_t)32 * 4096);
        }
        __syncthreads();

        f32x4 st[2][4] = {};
        __builtin_amdgcn_s_setprio(1);
#pragma unroll
        for (int kt = 0; kt < 4; ++kt) {
            bf16x8 ak0 = *(const bf16x8*)&Ks[(kt * 16 + l15) * 64 + ((quad ^ swz) << 3)];
            bf16x8 ak1 = *(const bf16x8*)&Ks[(kt * 16 + l15) * 64 + (((quad + 4) ^ swz) << 3)];
#pragma unroll
            for (int m = 0; m < 2; ++m) {
                st[m][kt] = __builtin_amdgcn_mfma_f32_16x16x32_bf16(ak0, aq[m][0], st[m][kt], 0, 0, 0);
                st[m][kt] = __builtin_amdgcn_mfma_f32_16x16x32_bf16(ak1, aq[m][1], st[m][kt], 0, 0, 0);
            }
        }
        __builtin_amdgcn_s_setprio(0);

        const bool diag = (kb == ntiles - 1);
        float alpha_[2];
        bool resc[2];
#pragma unroll
        for (int m = 0; m < 2; ++m) {
            float sv[16];
#pragma unroll
            for (int kt = 0; kt < 4; ++kt)
#pragma unroll
                for (int r = 0; r < 4; ++r) sv[kt * 4 + r] = st[m][kt][r];
            if (diag) {
                const int qg = qrow0 + m * 16 + l15;
#pragma unroll
                for (int kt = 0; kt < 4; ++kt)
#pragma unroll
                    for (int r = 0; r < 4; ++r) {
                        int key = kb * 64 + kt * 16 + quad * 4 + r;
                        if (key > qg) sv[kt * 4 + r] = -INFINITY;
                    }
            }
            float mx = sv[0];
#pragma unroll
            for (int i = 1; i < 16; ++i) mx = fmaxf(mx, sv[i]);
            mx = fmaxf(mx, __shfl_xor(mx, 16));
            mx = fmaxf(mx, __shfl_xor(mx, 32));
            mx *= SC;
            const float mold = m_i[m];
            const bool need = __any(mx > mold + 8.f);
            float al = 1.f;
            if (need) {
                const float mnew = fmaxf(mold, mx);
                al = __builtin_amdgcn_exp2f(mold - mnew);
                m_i[m] = mnew;
            }
            const float mu = m_i[m];
            float sum = 0.f;
#pragma unroll
            for (int i = 0; i < 16; ++i) {
                sv[i] = __builtin_amdgcn_exp2f(fmaf(sv[i], SC, -mu));
                sum += sv[i];
            }
            sum += __shfl_xor(sum, 16);
            sum += __shfl_xor(sum, 32);
            l_i[m] = l_i[m] * al + sum;
            alpha_[m] = al;
            resc[m] = need;

            u16* Pq = &Pw[w][m][0];
#pragma unroll
            for (int kt = 0; kt < 4; ++kt) {
                uint2 uu;
                uu.x = cvtpk(sv[kt * 4 + 0], sv[kt * 4 + 1]);
                uu.y = cvtpk(sv[kt * 4 + 2], sv[kt * 4 + 3]);
                *(uint2*)&Pq[l15 * 64 + (((2 * kt + (quad >> 1)) ^ swz) << 3) + ((quad & 1) << 2)] = uu;
            }
        }

#pragma unroll
        for (int m = 0; m < 2; ++m)
            if (resc[m]) {
                const float al = alpha_[m];
#pragma unroll
                for (int dt = 0; dt < 4; ++dt)
#pragma unroll
                    for (int r = 0; r < 4; ++r) acc[m][dt][r] *= al;
            }

        bf16x8 bp[2][2];
#pragma unroll
        for (int m = 0; m < 2; ++m) {
            const u16* Pq = &Pw[w][m][0];
            bp[m][0] = *(const bf16x8*)&Pq[l15 * 64 + ((quad ^ swz) << 3)];
            bp[m][1] = *(const bf16x8*)&Pq[l15 * 64 + (((quad + 4) ^ swz) << 3)];
        }

        __builtin_amdgcn_s_setprio(1);
#pragma unroll
        for (int dt = 0; dt < 4; ++dt) {
            bf16x8 av0 = *(const bf16x8*)&Vt[(dt * 16 + l15) * 64 + ((quad ^ swz) << 3)];
            bf16x8 av1 = *(const bf16x8*)&Vt[(dt * 16 + l15) * 64 + (((quad + 4) ^ swz) << 3)];
#pragma unroll
            for (int m = 0; m < 2; ++m) {
                acc[m][dt] = __builtin_amdgcn_mfma_f32_16x16x32_bf16(av0, bp[m][0], acc[m][dt], 0, 0, 0);
                acc[m][dt] = __builtin_amdgcn_mfma_f32_16x16x32_bf16(av1, bp[m][1], acc[m][dt], 0, 0, 0);
            }
        }
        __builtin_amdgcn_s_setprio(0);
    }

#pragma unroll
    for (int m = 0; m < 2; ++m) {
        float inv = 1.0f / l_i[m];
        size_t row = rowbase + qrow0 + m * 16 + l15;
#pragma unroll
        for (int dt = 0; dt < 4; ++dt) {
            uint2 uu;
            uu.x = cvtpk(acc[m][dt][0] * inv, acc[m][dt][1] * inv);
            uu.y = cvtpk(acc[m][dt][2] * inv, acc[m][dt][3] * inv);
            *(uint2*)&att[row * 2048 + h * 64 + dt * 16 + quad * 4] = uu;
        }
    }
}

// ---------------------------------------------------------------------------
extern "C" void kernel_launch(void* const* d_in, const int* in_sizes, int n_in,
                              void* d_out, int out_size, void* d_ws, size_t ws_size,
                              hipStream_t stream) {
    const float* x  = (const float*)d_in[0];
    const float* Wq = (const float*)d_in[2];
    const float* Wk = (const float*)d_in[3];
    const float* Wv = (const float*)d_in[4];
    const float* Wo = (const float*)d_in[5];
    float* out = (float*)d_out;

    u16* xb = (u16*)d_out;                                   // bf16 x in d_out (dead before final write)

    u16* q     = (u16*)d_ws;                                 // 4096x2048
    u16* kk    = q + (size_t)4096 * 2048;                    // 4096x512
    u16* vt    = kk + (size_t)4096 * 512;                    // 512x4096 (V^T)
    u16* wqkvt = vt + (size_t)4096 * 512;                    // 3072x2048 (dead after QKV gemm)
    u16* att   = wqkvt;                                      // 4096x2048 aliases dead wqkvt
    u16* wot   = kk;                                         // 2048x2048 aliases dead kk+vt (after attn)

    cvt_x<<<4096, 256, 0, stream>>>(x, xb);
    tcvt3<<<dim3(96, 64), 256, 0, stream>>>(Wq, Wk, Wv, wqkvt);
    gemm2<0><<<dim3(24, 32), 256, 0, stream>>>(xb, wqkvt, q, kk, vt, nullptr);  // rope fused
    attn8<<<1024, 256, 0, stream>>>(q, kk, vt, att);
    tcvt<<<dim3(64, 64), 256, 0, stream>>>(Wo, wot, 2048);
    gemm2<1><<<dim3(16, 32), 256, 0, stream>>>(att, wot, nullptr, nullptr, nullptr, out);
}

// Round 10
// 301.413 us; speedup vs baseline: 1.0970x; 1.0365x over previous
//
#include <hip/hip_runtime.h>
#include <cstdint>
#include <cstddef>

typedef unsigned short u16;
typedef __attribute__((ext_vector_type(8))) short bf16x8;
typedef __attribute__((ext_vector_type(8))) unsigned short u16x8;
typedef __attribute__((ext_vector_type(4))) unsigned short u16x4;
typedef __attribute__((ext_vector_type(4))) float f32x4;

__device__ __forceinline__ unsigned short f2bf(float f) {
    union { float f; uint32_t u; } c; c.f = f;
    uint32_t u = c.u + 0x7fffu + ((c.u >> 16) & 1u);
    return (unsigned short)(u >> 16);
}
__device__ __forceinline__ float bf2f(unsigned short h) {
    union { uint32_t u; float f; } c; c.u = ((uint32_t)h) << 16;
    return c.f;
}
// single-instruction pack: low16 = bf16(a), high16 = bf16(b)
__device__ __forceinline__ uint32_t cvtpk(float a, float b) {
    uint32_t r;
    asm("v_cvt_pk_bf16_f32 %0, %1, %2" : "=v"(r) : "v"(a), "v"(b));
    return r;
}

#define GLDS16(g, l)                                                               \
    __builtin_amdgcn_global_load_lds((const __attribute__((address_space(1))) void*)(g), \
                                     (__attribute__((address_space(3))) void*)(l), 16, 0, 0)

// ---------------------------------------------------------------------------
// prep: merged cvt_x + tcvt3(Wq|Wk|Wv) + optional tcvt(Wo) in ONE launch.
// Flat grid: [0,4096) cvt_x; [4096,10240) tcvt3; [10240,14336) Wo transpose.
// Launch with 10240 blocks to skip the Wo part (small-ws fallback).
// ---------------------------------------------------------------------------
__global__ __launch_bounds__(256) void prep(const float* __restrict__ x,
                                            const float* __restrict__ Wq,
                                            const float* __restrict__ Wk,
                                            const float* __restrict__ Wv,
                                            const float* __restrict__ Wo,
                                            u16* __restrict__ xb,
                                            u16* __restrict__ wqkvt,
                                            u16* __restrict__ wot) {
    __shared__ u16 tile[32][33];
    const int id = blockIdx.x;
    const int t = threadIdx.x;

    if (id < 4096) {  // ---- cvt_x ----
        int i = id * 256 + t;
        const float4* s = (const float4*)x + (size_t)i * 2;
        float4 a = s[0], b = s[1];
        u16x8 o;
        o[0] = f2bf(a.x); o[1] = f2bf(a.y); o[2] = f2bf(a.z); o[3] = f2bf(a.w);
        o[4] = f2bf(b.x); o[5] = f2bf(b.y); o[6] = f2bf(b.z); o[7] = f2bf(b.w);
        *(u16x8*)(xb + (size_t)i * 8) = o;
        return;
    }

    const float* src; int C, nb, by; u16* dbase;
    if (id < 10240) {  // ---- tcvt3 ----
        int r = id - 4096;
        int bxg = r % 96; by = r / 96;
        if (bxg < 64)      { src = Wq; C = 2048; nb = bxg;      dbase = wqkvt; }
        else if (bxg < 80) { src = Wk; C = 512;  nb = bxg - 64; dbase = wqkvt + (size_t)2048 * 2048; }
        else               { src = Wv; C = 512;  nb = bxg - 80; dbase = wqkvt + (size_t)2560 * 2048; }
    } else {           // ---- tcvt(Wo) ----
        int r = id - 10240;
        nb = r % 64; by = r / 64; src = Wo; C = 2048; dbase = wot;
    }
    const int tr = t >> 3, tc = (t & 7) << 2;
    float4 f = *(const float4*)&src[(size_t)(by * 32 + tr) * C + nb * 32 + tc];
    tile[tr][tc + 0] = f2bf(f.x); tile[tr][tc + 1] = f2bf(f.y);
    tile[tr][tc + 2] = f2bf(f.z); tile[tr][tc + 3] = f2bf(f.w);
    __syncthreads();
    u16x4 o;
    o[0] = tile[tc + 0][tr]; o[1] = tile[tc + 1][tr];
    o[2] = tile[tc + 2][tr]; o[3] = tile[tc + 3][tr];
    *(u16x4*)&dbase[(size_t)(nb * 32 + tr) * 2048 + by * 32 + tc] = o;
}

// Standalone Wo transpose (small-ws fallback, runs after attn when wot aliases kk).
__global__ __launch_bounds__(256) void tcvt(const float* __restrict__ src,
                                            u16* __restrict__ dst, int C) {
    __shared__ u16 tile[32][33];
    const int t = threadIdx.x;
    const int bx = blockIdx.x, by = blockIdx.y;
    const int tr = t >> 3, tc = (t & 7) << 2;
    float4 f = *(const float4*)&src[(size_t)(by * 32 + tr) * C + bx * 32 + tc];
    tile[tr][tc + 0] = f2bf(f.x); tile[tr][tc + 1] = f2bf(f.y);
    tile[tr][tc + 2] = f2bf(f.z); tile[tr][tc + 3] = f2bf(f.w);
    __syncthreads();
    u16x4 o;
    o[0] = tile[tc + 0][tr]; o[1] = tile[tc + 1][tr];
    o[2] = tile[tc + 2][tr]; o[3] = tile[tc + 3][tr];
    *(u16x4*)&dst[(size_t)(bx * 32 + tr) * 2048 + by * 32 + tc] = o;
}

// ---------------------------------------------------------------------------
// m97-style GEMM: C[M x N] = A[M x 2048] * Bt[N x 2048]^T, bf16 inputs.
// MODE 0: segmented qkv epilogue with FUSED ROPE (q,k roped; v transposed).
// MODE 1: fp32 C, N=2048.
// ---------------------------------------------------------------------------
template <int MODE>
__global__ __launch_bounds__(256) void gemm2(const u16* __restrict__ A,
                                             const u16* __restrict__ Bt,
                                             u16* __restrict__ oq, u16* __restrict__ ok,
                                             u16* __restrict__ ov, float* __restrict__ of) {
    __shared__ u16 As[128 * 32];
    __shared__ u16 Bs[128 * 32];
    const int t = threadIdx.x, w = t >> 6, lane = t & 63;
    const int l15 = lane & 15, quad = lane >> 4;
    const int m0 = blockIdx.y << 7, n0 = blockIdx.x << 7;
    const int K = 2048;
    const int c0 = w * 2, c1 = c0 + 1;
    const int ar0 = c0 * 16 + (lane >> 2), ar1 = c1 * 16 + (lane >> 2);
    const int ac = (lane & 3) << 3;
    const u16* Ap0 = A + (size_t)(m0 + ar0) * K + ac;
    const u16* Ap1 = A + (size_t)(m0 + ar1) * K + ac;
    const u16* Bp0 = Bt + (size_t)(n0 + ar0) * K + ac;
    const u16* Bp1 = Bt + (size_t)(n0 + ar1) * K + ac;
    const int wm = (w >> 1) << 6, wn = (w & 1) << 6;

    f32x4 acc[4][4] = {};

    for (int k0 = 0; k0 < K; k0 += 32) {
        GLDS16(Ap0 + k0, &As[c0 * 512]);
        GLDS16(Ap1 + k0, &As[c1 * 512]);
        GLDS16(Bp0 + k0, &Bs[c0 * 512]);
        GLDS16(Bp1 + k0, &Bs[c1 * 512]);
        __syncthreads();
        bf16x8 a[4], bfr[4];
#pragma unroll
        for (int mt = 0; mt < 4; ++mt)
            a[mt] = *(bf16x8*)&As[(wm + mt * 16 + l15) * 32 + quad * 8];
#pragma unroll
        for (int nt = 0; nt < 4; ++nt)
            bfr[nt] = *(bf16x8*)&Bs[(wn + nt * 16 + l15) * 32 + quad * 8];
#pragma unroll
        for (int mt = 0; mt < 4; ++mt)
#pragma unroll
            for (int nt = 0; nt < 4; ++nt)
                acc[mt][nt] = __builtin_amdgcn_mfma_f32_16x16x32_bf16(a[mt], bfr[nt], acc[mt][nt], 0, 0, 0);
        __syncthreads();
    }

    if constexpr (MODE == 0) {
        const int colbase = n0 + wn;
        const bool isv = (colbase >= 2560);
        float iv[4];
        if (!isv) {
#pragma unroll
            for (int nt = 0; nt < 4; ++nt)
                iv[nt] = exp2f(-0.4152410118609253f * (float)(nt * 8 + (l15 >> 1)));
        }
        const int map1 = (quad << 4) | ((2 * l15 + 1) & 15);  // odd partners (d<32)
        const int map2 = (quad << 4) | ((2 * l15) & 15);      // even partners (d>=32)
        const bool lo = (l15 < 8);
#pragma unroll
        for (int mt = 0; mt < 4; ++mt)
#pragma unroll
            for (int r = 0; r < 4; ++r) {
                const int row = m0 + wm + mt * 16 + quad * 4 + r;
                float v0 = acc[mt][0][r], v1 = acc[mt][1][r];
                float v2 = acc[mt][2][r], v3 = acc[mt][3][r];
                float o0 = v0, o1 = v1, o2 = v2, o3 = v3;
                if (!isv) {
                    float g1a = __shfl(v0, map1), g1b = __shfl(v1, map1);
                    float g1c = __shfl(v2, map1), g1d = __shfl(v3, map1);
                    float g2a = __shfl(v0, map2), g2b = __shfl(v1, map2);
                    float g2c = __shfl(v2, map2), g2d = __shfl(v3, map2);
                    float p0 = lo ? g1a : g1b;
                    float p1 = lo ? g1c : g1d;
                    float p2 = lo ? g2a : g2b;
                    float p3 = lo ? g2c : g2d;
                    const float tt = (float)(row & 2047);
                    float sn, cs;
                    __sincosf(tt * iv[0], &sn, &cs); o0 = v0 * cs - p0 * sn;
                    __sincosf(tt * iv[1], &sn, &cs); o1 = v1 * cs - p1 * sn;
                    __sincosf(tt * iv[2], &sn, &cs); o2 = v2 * cs + p2 * sn;
                    __sincosf(tt * iv[3], &sn, &cs); o3 = v3 * cs + p3 * sn;
                }
                float o[4] = {o0, o1, o2, o3};
                if (colbase < 2048) {
#pragma unroll
                    for (int nt = 0; nt < 4; ++nt)
                        oq[(size_t)row * 2048 + colbase + nt * 16 + l15] = f2bf(o[nt]);
                } else if (colbase < 2560) {
#pragma unroll
                    for (int nt = 0; nt < 4; ++nt)
                        ok[(size_t)row * 512 + colbase - 2048 + nt * 16 + l15] = f2bf(o[nt]);
                } else {
#pragma unroll
                    for (int nt = 0; nt < 4; ++nt)
                        ov[(size_t)(colbase - 2560 + nt * 16 + l15) * 4096 + row] = f2bf(o[nt]);
                }
            }
    } else {
#pragma unroll
        for (int mt = 0; mt < 4; ++mt)
#pragma unroll
            for (int nt = 0; nt < 4; ++nt)
#pragma unroll
                for (int r = 0; r < 4; ++r) {
                    int row = m0 + wm + mt * 16 + quad * 4 + r;
                    int col = n0 + wn + nt * 16 + l15;
                    of[(size_t)row * 2048 + col] = acc[mt][nt][r];
                }
    }
}

// ---------------------------------------------------------------------------
// Flash attention v10 — K/V double-buffer, 1 barrier/tile, SEPARATE per-
// (wave,m) Pw buffers (attn8's verbatim P-handling; R9's shared-Pw reuse had
// a same-wave WAR the compiler may reorder under strict aliasing — reverted).
// Staging placement = R2's attn6 (passed refcheck): after S-MFMA, before PV.
// LDS 48KB -> 3 blocks/CU. launch_bounds(256,2): VGPR cap 128, no spill.
// ---------------------------------------------------------------------------
__global__ __launch_bounds__(256, 2) void attn10(const u16* __restrict__ q,
                                                 const u16* __restrict__ k,
                                                 const u16* __restrict__ vT,
                                                 u16* __restrict__ att) {
    __shared__ u16 Ks[2][64 * 64];      // [buf][key][d] swizzled, 128B rows
    __shared__ u16 Vt[2][64 * 64];      // [buf][d][key] swizzled
    __shared__ u16 Pw[4][2][16 * 64];   // per (wave, stream) P^T, swizzled

    const int t = threadIdx.x, w = t >> 6, lane = t & 63;
    const int l15 = lane & 15, quad = lane >> 4;
    const int id = blockIdx.x;
    const int kvh = id & 7;
    const int z = (id >> 3) & 1;
    const int gi = id >> 4;             // 0..63
    const int p = gi & 15;
    int g;
    switch (gi >> 4) {
        case 0:  g = 63 - p; break;
        case 1:  g = 32 + p; break;
        case 2:  g = 31 - p; break;
        default: g = p;      break;
    }
    const int h = kvh * 4 + w;
    const size_t rowbase = (size_t)z * 2048;
    const float SC = 0.125f * 1.4426950408889634f;  // 1/sqrt(64) * log2(e)
    const int swz = l15 & 7;

    const int srow = t >> 3;            // 0..31 (second row = srow+32)
    const int slot = t & 7;
    const int sd = slot << 3;
    const int lidx = srow * 64 + ((slot ^ (srow & 7)) << 3);

    const u16* kbase = &k[(rowbase + srow) * 512 + kvh * 64 + sd];
    const u16* vbase = &vT[(size_t)(kvh * 64 + srow) * 4096 + rowbase + sd];

    const int ntiles = (g >> 1) + 1;
    const int qrow0 = g * 32;

    bf16x8 aq[2][2];
#pragma unroll
    for (int m = 0; m < 2; ++m)
#pragma unroll
        for (int kc = 0; kc < 2; ++kc)
            aq[m][kc] = *(const bf16x8*)&q[(rowbase + qrow0 + m * 16 + l15) * 2048 +
                                           h * 64 + kc * 32 + quad * 8];

    f32x4 acc[2][4] = {};
    float m_i[2] = {-INFINITY, -INFINITY};
    float l_i[2] = {0.f, 0.f};

    // prologue: stage tile0 -> buf0; prefetch tile1 into regs
    u16x8 pk0 = *(const u16x8*)kbase;
    u16x8 pk1 = *(const u16x8*)(kbase + (size_t)32 * 512);
    u16x8 pv0 = *(const u16x8*)vbase;
    u16x8 pv1 = *(const u16x8*)(vbase + (size_t)32 * 4096);
    *(u16x8*)&Ks[0][lidx]        = pk0;
    *(u16x8*)&Ks[0][lidx + 2048] = pk1;
    *(u16x8*)&Vt[0][lidx]        = pv0;
    *(u16x8*)&Vt[0][lidx + 2048] = pv1;
    if (ntiles > 1) {
        const u16* kp = kbase + (size_t)64 * 512;
        pk0 = *(const u16x8*)kp;
        pk1 = *(const u16x8*)(kp + (size_t)32 * 512);
        const u16* vp = vbase + 64;
        pv0 = *(const u16x8*)vp;
        pv1 = *(const u16x8*)(vp + (size_t)32 * 4096);
    }
    __syncthreads();

    for (int kb = 0; kb < ntiles; ++kb) {
        const int cur = kb & 1;

        // S^T from Ks[cur]
        f32x4 st[2][4] = {};
        __builtin_amdgcn_s_setprio(1);
#pragma unroll
        for (int kt = 0; kt < 4; ++kt) {
            bf16x8 ak0 = *(const bf16x8*)&Ks[cur][(kt * 16 + l15) * 64 + ((quad ^ swz) << 3)];
            bf16x8 ak1 = *(const bf16x8*)&Ks[cur][(kt * 16 + l15) * 64 + (((quad + 4) ^ swz) << 3)];
#pragma unroll
            for (int m = 0; m < 2; ++m) {
                st[m][kt] = __builtin_amdgcn_mfma_f32_16x16x32_bf16(ak0, aq[m][0], st[m][kt], 0, 0, 0);
                st[m][kt] = __builtin_amdgcn_mfma_f32_16x16x32_bf16(ak1, aq[m][1], st[m][kt], 0, 0, 0);
            }
        }
        __builtin_amdgcn_s_setprio(0);

        const bool diag = (kb == ntiles - 1);
        float alpha_[2];
        bool resc[2];
#pragma unroll
        for (int m = 0; m < 2; ++m) {
            float sv[16];
#pragma unroll
            for (int kt = 0; kt < 4; ++kt)
#pragma unroll
                for (int r = 0; r < 4; ++r) sv[kt * 4 + r] = st[m][kt][r];
            if (diag) {
                const int qg = qrow0 + m * 16 + l15;
#pragma unroll
                for (int kt = 0; kt < 4; ++kt)
#pragma unroll
                    for (int r = 0; r < 4; ++r) {
                        int key = kb * 64 + kt * 16 + quad * 4 + r;
                        if (key > qg) sv[kt * 4 + r] = -INFINITY;
                    }
            }
            float mx = sv[0];
#pragma unroll
            for (int i = 1; i < 16; ++i) mx = fmaxf(mx, sv[i]);
            mx = fmaxf(mx, __shfl_xor(mx, 16));
            mx = fmaxf(mx, __shfl_xor(mx, 32));
            mx *= SC;
            const float mold = m_i[m];
            const bool need = __any(mx > mold + 8.f);
            float al = 1.f;
            if (need) {
                const float mnew = fmaxf(mold, mx);
                al = __builtin_amdgcn_exp2f(mold - mnew);
                m_i[m] = mnew;
            }
            const float mu = m_i[m];
            float sum = 0.f;
#pragma unroll
            for (int i = 0; i < 16; ++i) {
                sv[i] = __builtin_amdgcn_exp2f(fmaf(sv[i], SC, -mu));
                sum += sv[i];
            }
            sum += __shfl_xor(sum, 16);
            sum += __shfl_xor(sum, 32);
            l_i[m] = l_i[m] * al + sum;
            alpha_[m] = al;
            resc[m] = need;

            u16* Pq = &Pw[w][m][0];
#pragma unroll
            for (int kt = 0; kt < 4; ++kt) {
                uint2 uu;
                uu.x = cvtpk(sv[kt * 4 + 0], sv[kt * 4 + 1]);
                uu.y = cvtpk(sv[kt * 4 + 2], sv[kt * 4 + 3]);
                *(uint2*)&Pq[l15 * 64 + (((2 * kt + (quad >> 1)) ^ swz) << 3) + ((quad & 1) << 2)] = uu;
            }
        }

        // stage next tile into buf cur^1 (attn6's proven position); prefetch kb+2
        if (kb + 1 < ntiles) {
            const int nx = cur ^ 1;
            *(u16x8*)&Ks[nx][lidx]        = pk0;
            *(u16x8*)&Ks[nx][lidx + 2048] = pk1;
            *(u16x8*)&Vt[nx][lidx]        = pv0;
            *(u16x8*)&Vt[nx][lidx + 2048] = pv1;
            if (kb + 2 < ntiles) {
                const u16* kp = kbase + (size_t)(kb + 2) * 64 * 512;
                pk0 = *(const u16x8*)kp;
                pk1 = *(const u16x8*)(kp + (size_t)32 * 512);
                const u16* vp = vbase + (size_t)(kb + 2) * 64;
                pv0 = *(const u16x8*)vp;
                pv1 = *(const u16x8*)(vp + (size_t)32 * 4096);
            }
        }

        // deferred rescale (wave-uniform)
#pragma unroll
        for (int m = 0; m < 2; ++m)
            if (resc[m]) {
                const float al = alpha_[m];
#pragma unroll
                for (int dt = 0; dt < 4; ++dt)
#pragma unroll
                    for (int r = 0; r < 4; ++r) acc[m][dt][r] *= al;
            }

        // P fragments (separate buffers per m — no same-buffer WAR)
        bf16x8 bp[2][2];
#pragma unroll
        for (int m = 0; m < 2; ++m) {
            const u16* Pq = &Pw[w][m][0];
            bp[m][0] = *(const bf16x8*)&Pq[l15 * 64 + ((quad ^ swz) << 3)];
            bp[m][1] = *(const bf16x8*)&Pq[l15 * 64 + (((quad + 4) ^ swz) << 3)];
        }

        // PV from Vt[cur]
        __builtin_amdgcn_s_setprio(1);
#pragma unroll
        for (int dt = 0; dt < 4; ++dt) {
            bf16x8 av0 = *(const bf16x8*)&Vt[cur][(dt * 16 + l15) * 64 + ((quad ^ swz) << 3)];
            bf16x8 av1 = *(const bf16x8*)&Vt[cur][(dt * 16 + l15) * 64 + (((quad + 4) ^ swz) << 3)];
#pragma unroll
            for (int m = 0; m < 2; ++m) {
                acc[m][dt] = __builtin_amdgcn_mfma_f32_16x16x32_bf16(av0, bp[m][0], acc[m][dt], 0, 0, 0);
                acc[m][dt] = __builtin_amdgcn_mfma_f32_16x16x32_bf16(av1, bp[m][1], acc[m][dt], 0, 0, 0);
            }
        }
        __builtin_amdgcn_s_setprio(0);
        __syncthreads();   // single barrier per tile
    }

#pragma unroll
    for (int m = 0; m < 2; ++m) {
        float inv = 1.0f / l_i[m];
        size_t row = rowbase + qrow0 + m * 16 + l15;
#pragma unroll
        for (int dt = 0; dt < 4; ++dt) {
            uint2 uu;
            uu.x = cvtpk(acc[m][dt][0] * inv, acc[m][dt][1] * inv);
            uu.y = cvtpk(acc[m][dt][2] * inv, acc[m][dt][3] * inv);
            *(uint2*)&att[row * 2048 + h * 64 + dt * 16 + quad * 4] = uu;
        }
    }
}

// ---------------------------------------------------------------------------
extern "C" void kernel_launch(void* const* d_in, const int* in_sizes, int n_in,
                              void* d_out, int out_size, void* d_ws, size_t ws_size,
                              hipStream_t stream) {
    const float* x  = (const float*)d_in[0];
    const float* Wq = (const float*)d_in[2];
    const float* Wk = (const float*)d_in[3];
    const float* Wv = (const float*)d_in[4];
    const float* Wo = (const float*)d_in[5];
    float* out = (float*)d_out;

    u16* xb = (u16*)d_out;                                   // bf16 x in d_out (dead before final write)

    u16* q     = (u16*)d_ws;                                 // 4096x2048
    u16* kk    = q + (size_t)4096 * 2048;                    // 4096x512
    u16* vt    = kk + (size_t)4096 * 512;                    // 512x4096 (V^T)
    u16* wqkvt = vt + (size_t)4096 * 512;                    // 3072x2048 (dead after QKV gemm)
    u16* att   = wqkvt;                                      // 4096x2048 aliases dead wqkvt
    u16* wot_sep = att + (size_t)4096 * 2048;                // 2048x2048 (large-ws path)

    const size_t need = ((size_t)4096 * 2048 + 4096 * 512 + 512 * 4096 +
                         (size_t)4096 * 2048 + (size_t)2048 * 2048) * 2;

    if (ws_size >= need) {
        prep<<<14336, 256, 0, stream>>>(x, Wq, Wk, Wv, Wo, xb, wqkvt, wot_sep);
        gemm2<0><<<dim3(24, 32), 256, 0, stream>>>(xb, wqkvt, q, kk, vt, nullptr);  // rope fused
        attn10<<<1024, 256, 0, stream>>>(q, kk, vt, att);
        gemm2<1><<<dim3(16, 32), 256, 0, stream>>>(att, wot_sep, nullptr, nullptr, nullptr, out);
    } else {
        u16* wot = kk;                                       // aliases dead kk+vt (after attn)
        prep<<<10240, 256, 0, stream>>>(x, Wq, Wk, Wv, Wo, xb, wqkvt, nullptr);
        gemm2<0><<<dim3(24, 32), 256, 0, stream>>>(xb, wqkvt, q, kk, vt, nullptr);
        attn10<<<1024, 256, 0, stream>>>(q, kk, vt, att);
        tcvt<<<dim3(64, 64), 256, 0, stream>>>(Wo, wot, 2048);
        gemm2<1><<<dim3(16, 32), 256, 0, stream>>>(att, wot, nullptr, nullptr, nullptr, out);
    }
}